// Round 6
// baseline (3916.261 us; speedup 1.0000x reference)
//
#include <hip/hip_runtime.h>
#include <stdint.h>
#include <stddef.h>

// ---------------------------------------------------------------------------
// GRBM Gibbs sampling, round 6. Exact JAX threefry numerics — every output
// keeps ONE ascending-k fmaf chain -> absmax must stay exactly 0.1015625.
// R5 post-mortem: L's KT=32/1-barrier validated the LDS-read-bound model
// (157us ~= 2x82 FMA floor at 4x4 micro). V regressed with 1-barrier ->
// revert V to R4's proven 2-barrier schedule (172us).
// R6: L upgraded to 8x4 micro (1.5x LDS bound, predict ~135us); V = R4 verbatim.
// ---------------------------------------------------------------------------

__host__ __device__ inline void threefry2x32(uint32_t k0, uint32_t k1,
                                             uint32_t x0, uint32_t x1,
                                             uint32_t& o0, uint32_t& o1) {
  uint32_t ks2 = k0 ^ k1 ^ 0x1BD11BDAu;
  x0 += k0; x1 += k1;
#define TFR(r) { x0 += x1; x1 = (x1 << (r)) | (x1 >> (32 - (r))); x1 ^= x0; }
  TFR(13) TFR(15) TFR(26) TFR(6)
  x0 += k1;  x1 += ks2 + 1u;
  TFR(17) TFR(29) TFR(16) TFR(24)
  x0 += ks2; x1 += k0 + 2u;
  TFR(13) TFR(15) TFR(26) TFR(6)
  x0 += k0;  x1 += k1 + 3u;
  TFR(17) TFR(29) TFR(16) TFR(24)
  x0 += k1;  x1 += ks2 + 4u;
  TFR(13) TFR(15) TFR(26) TFR(6)
  x0 += ks2; x1 += k0 + 5u;
#undef TFR
  o0 = x0; o1 = x1;
}

__device__ inline float jax_uniform01(uint32_t key0, uint32_t key1, uint32_t idx) {
  uint32_t o0, o1;
  threefry2x32(key0, key1, 0u, idx, o0, o1);
  uint32_t bits = o0 ^ o1;
  return __uint_as_float((bits >> 9) | 0x3f800000u) - 1.0f;
}

__device__ inline float erfinv_xla(float x) {
  float w = -log1pf(-x * x);
  float p;
  if (w < 5.0f) {
    w = w - 2.5f;
    p = 2.81022636e-08f;
    p = fmaf(p, w, 3.43273939e-07f);
    p = fmaf(p, w, -3.5233877e-06f);
    p = fmaf(p, w, -4.39150654e-06f);
    p = fmaf(p, w, 0.00021858087f);
    p = fmaf(p, w, -0.00125372503f);
    p = fmaf(p, w, -0.00417768164f);
    p = fmaf(p, w, 0.246640727f);
    p = fmaf(p, w, 1.50140941f);
  } else {
    w = sqrtf(w) - 3.0f;
    p = -0.000200214257f;
    p = fmaf(p, w, 0.000100950558f);
    p = fmaf(p, w, 0.00134934322f);
    p = fmaf(p, w, -0.00367342844f);
    p = fmaf(p, w, 0.00573950773f);
    p = fmaf(p, w, -0.0076224613f);
    p = fmaf(p, w, 0.00943887047f);
    p = fmaf(p, w, 1.00167406f);
    p = fmaf(p, w, 2.83297682f);
  }
  return p * x;
}

__global__ void prep_kernel(const float* __restrict__ log_var,
                            float* __restrict__ invvar,
                            float* __restrict__ stdv, int V) {
  int i = blockIdx.x * 256 + threadIdx.x;
  if (i < V) {
    float var = fmaxf(expf(log_var[i]), 1e-8f);
    invvar[i] = 1.0f / var;
    stdv[i] = sqrtf(var);
  }
}

// ---------------------------------------------------------------------------
// Kernel L: logits = (Vin*invvar) @ W + b ; h = bernoulli(sigmoid(logits))
// M=4096, N=512, K=3072. BM=128, BN=64, 256 thr, micro 8(m)x4(n).
// KT=32, single-barrier dbuf. grid=256 (1 blk/CU); mb=bid&31, nb=bid>>5
// puts all 8 col-blocks of a Vin row-panel on one XCD (bid%8 == mb%8).
// ---------------------------------------------------------------------------
__global__ __launch_bounds__(256, 1)
void gemm_logit_bern(const float* __restrict__ Vin, const float* __restrict__ Wm,
                     const float* __restrict__ bias, const float* __restrict__ invvar,
                     uint8_t* __restrict__ Hout, uint32_t kb0, uint32_t kb1) {
  const int N = 512, K = 3072;
  const int KT = 32;
  __shared__ float As[2][KT][132];   // [k][m], +4 pad ; 33.8 KB
  __shared__ float Bs[2][KT][68];    // [k][n], +4 pad ; 17.4 KB

  const int tid = threadIdx.x;
  const int bid = blockIdx.x;            // 0..255
  const int mb = bid & 31;               // 0..31  (XCD = bid%8 = mb%8)
  const int nb = bid >> 5;               // 0..7
  const int mBase = mb * 128, nBase = nb * 64;

  const int tx = tid & 15, ty = tid >> 4;   // n(4 each), m(8 each)
  const int am = tid >> 2;               // 0..63 ; rows am, am+64
  const int ak = (tid & 3) * 4;          // 0,4,8,12 ; +16 second half
  const int bk = tid >> 4;               // 0..15    ; +16 second half
  const int bn = (tid & 15) * 4;         // 0..60

  float acc[8][4] = {};

  float4 ra00, ra01, ra10, ra11, riv0, riv1, rb0, rb1;

#define LOADL(t) { \
  int k0 = (t) * KT; \
  ra00 = *reinterpret_cast<const float4*>(&Vin[(size_t)(mBase + am) * K + k0 + ak]); \
  ra01 = *reinterpret_cast<const float4*>(&Vin[(size_t)(mBase + am) * K + k0 + 16 + ak]); \
  ra10 = *reinterpret_cast<const float4*>(&Vin[(size_t)(mBase + am + 64) * K + k0 + ak]); \
  ra11 = *reinterpret_cast<const float4*>(&Vin[(size_t)(mBase + am + 64) * K + k0 + 16 + ak]); \
  riv0 = *reinterpret_cast<const float4*>(&invvar[k0 + ak]); \
  riv1 = *reinterpret_cast<const float4*>(&invvar[k0 + 16 + ak]); \
  rb0  = *reinterpret_cast<const float4*>(&Wm[(size_t)(k0 + bk) * N + nBase + bn]); \
  rb1  = *reinterpret_cast<const float4*>(&Wm[(size_t)(k0 + 16 + bk) * N + nBase + bn]); }

#define STOREL(p) { \
  As[p][ak + 0][am]       = ra00.x * riv0.x; \
  As[p][ak + 1][am]       = ra00.y * riv0.y; \
  As[p][ak + 2][am]       = ra00.z * riv0.z; \
  As[p][ak + 3][am]       = ra00.w * riv0.w; \
  As[p][ak + 16][am]      = ra01.x * riv1.x; \
  As[p][ak + 17][am]      = ra01.y * riv1.y; \
  As[p][ak + 18][am]      = ra01.z * riv1.z; \
  As[p][ak + 19][am]      = ra01.w * riv1.w; \
  As[p][ak + 0][am + 64]  = ra10.x * riv0.x; \
  As[p][ak + 1][am + 64]  = ra10.y * riv0.y; \
  As[p][ak + 2][am + 64]  = ra10.z * riv0.z; \
  As[p][ak + 3][am + 64]  = ra10.w * riv0.w; \
  As[p][ak + 16][am + 64] = ra11.x * riv1.x; \
  As[p][ak + 17][am + 64] = ra11.y * riv1.y; \
  As[p][ak + 18][am + 64] = ra11.z * riv1.z; \
  As[p][ak + 19][am + 64] = ra11.w * riv1.w; \
  *reinterpret_cast<float4*>(&Bs[p][bk][bn])      = rb0; \
  *reinterpret_cast<float4*>(&Bs[p][bk + 16][bn]) = rb1; }

  LOADL(0)

  int p = 0;
  const int NT = K / KT;   // 96
  for (int t = 0; t < NT; ++t) {
    STOREL(p)
    if (t + 1 < NT) LOADL(t + 1)
    __syncthreads();
#pragma unroll
    for (int kk = 0; kk < KT; ++kk) {
      float4 x0 = *reinterpret_cast<const float4*>(&As[p][kk][ty * 8]);
      float4 x1 = *reinterpret_cast<const float4*>(&As[p][kk][ty * 8 + 4]);
      float4 y  = *reinterpret_cast<const float4*>(&Bs[p][kk][tx * 4]);
#define LROW(i, a) \
      acc[i][0] = fmaf(a, y.x, acc[i][0]); \
      acc[i][1] = fmaf(a, y.y, acc[i][1]); \
      acc[i][2] = fmaf(a, y.z, acc[i][2]); \
      acc[i][3] = fmaf(a, y.w, acc[i][3]);
      LROW(0, x0.x) LROW(1, x0.y) LROW(2, x0.z) LROW(3, x0.w)
      LROW(4, x1.x) LROW(5, x1.y) LROW(6, x1.z) LROW(7, x1.w)
#undef LROW
    }
    p ^= 1;
  }
#undef LOADL
#undef STOREL

#pragma unroll
  for (int i = 0; i < 8; ++i) {
    int row = mBase + ty * 8 + i;
    uint32_t hp = 0;
#pragma unroll
    for (int j = 0; j < 4; ++j) {
      int col = nBase + tx * 4 + j;
      float logit = acc[i][j] + bias[col];
      float p2 = 0.5f + 0.5f * tanhf(0.5f * logit);
      uint32_t idx = (uint32_t)row * (uint32_t)N + (uint32_t)col;
      float u = jax_uniform01(kb0, kb1, idx);
      hp |= ((u < p2) ? 1u : 0u) << (8 * j);
    }
    *reinterpret_cast<uint32_t*>(&Hout[(size_t)row * N + nBase + tx * 4]) = hp;
  }
}

// ---------------------------------------------------------------------------
// Kernel V (R4 verbatim — proven 172us): v = h @ W^T + mu + normal*std.
// M=4096, N=3072, K=512. BM=128, BN=64, 256 thr, micro 8x4, KT=16,
// 2-barrier dbuf (LOAD t+1 -> COMPUTE cur -> sync -> STAGE -> sync).
// grid=(48,32): natural dispatch gives same-XCD W n-panels (48%8==0).
// ---------------------------------------------------------------------------
__global__ __launch_bounds__(256, 2)
void gemm_v_sample(const uint8_t* __restrict__ Hin, const float* __restrict__ Wm,
                   const float* __restrict__ muv, const float* __restrict__ stdv,
                   float* __restrict__ Vout, uint32_t kn0, uint32_t kn1) {
  const int N = 3072, K = 512;
  const int KT = 16;
  __shared__ float As[2][KT][132];   // [k][m 0..127]
  __shared__ float Bs[2][KT][68];    // [k][n 0..63]

  const int tid = threadIdx.x;
  const int mBase = blockIdx.y * 128, nBase = blockIdx.x * 64;
  const int tx = tid & 15, ty = tid >> 4;

  const int am = tid >> 1;               // 0..127
  const int ah = (tid & 1) * 8;          // 0,8
  const int bn = tid >> 2;               // 0..63
  const int bq = (tid & 3) * 4;          // 0,4,8,12

  float acc[8][4] = {};

  uint32_t rh0, rh1;
  float4 rb;
  {
    const uint32_t* hp_ = reinterpret_cast<const uint32_t*>(&Hin[(size_t)(mBase + am) * K + ah]);
    rh0 = hp_[0]; rh1 = hp_[1];
  }
  rb = *reinterpret_cast<const float4*>(&Wm[(size_t)(nBase + bn) * K + bq]);

#define STAGE_V(buf) { \
  As[buf][ah + 0][am] = (float)((rh0 >> 0) & 0xffu); \
  As[buf][ah + 1][am] = (float)((rh0 >> 8) & 0xffu); \
  As[buf][ah + 2][am] = (float)((rh0 >> 16) & 0xffu); \
  As[buf][ah + 3][am] = (float)((rh0 >> 24) & 0xffu); \
  As[buf][ah + 4][am] = (float)((rh1 >> 0) & 0xffu); \
  As[buf][ah + 5][am] = (float)((rh1 >> 8) & 0xffu); \
  As[buf][ah + 6][am] = (float)((rh1 >> 16) & 0xffu); \
  As[buf][ah + 7][am] = (float)((rh1 >> 24) & 0xffu); \
  Bs[buf][bq + 0][bn] = rb.x; \
  Bs[buf][bq + 1][bn] = rb.y; \
  Bs[buf][bq + 2][bn] = rb.z; \
  Bs[buf][bq + 3][bn] = rb.w; }

  STAGE_V(0)
  __syncthreads();

  int cur = 0;
  const int NT = K / KT;   // 32
  for (int t = 0; t < NT; ++t) {
    const bool more = (t + 1 < NT);
    if (more) {
      int k0 = (t + 1) * KT;
      const uint32_t* hp_ = reinterpret_cast<const uint32_t*>(&Hin[(size_t)(mBase + am) * K + k0 + ah]);
      rh0 = hp_[0]; rh1 = hp_[1];
      rb = *reinterpret_cast<const float4*>(&Wm[(size_t)(nBase + bn) * K + k0 + bq]);
    }
#pragma unroll
    for (int kk = 0; kk < KT; ++kk) {
      float4 x0 = *reinterpret_cast<const float4*>(&As[cur][kk][ty * 8]);
      float4 x1 = *reinterpret_cast<const float4*>(&As[cur][kk][ty * 8 + 4]);
      float4 y  = *reinterpret_cast<const float4*>(&Bs[cur][kk][tx * 4]);
#define VROW(i, a) \
      acc[i][0] = fmaf(a, y.x, acc[i][0]); \
      acc[i][1] = fmaf(a, y.y, acc[i][1]); \
      acc[i][2] = fmaf(a, y.z, acc[i][2]); \
      acc[i][3] = fmaf(a, y.w, acc[i][3]);
      VROW(0, x0.x) VROW(1, x0.y) VROW(2, x0.z) VROW(3, x0.w)
      VROW(4, x1.x) VROW(5, x1.y) VROW(6, x1.z) VROW(7, x1.w)
#undef VROW
    }
    if (more) {
      __syncthreads();
      STAGE_V(cur ^ 1)
      __syncthreads();
      cur ^= 1;
    }
  }
#undef STAGE_V

  const float LO = -0.99999994f;
  const float SQRT2 = 1.41421356237f;
  const float4 mu4 = *reinterpret_cast<const float4*>(&muv[nBase + tx * 4]);
  const float4 sd4 = *reinterpret_cast<const float4*>(&stdv[nBase + tx * 4]);
  const float mur[4] = {mu4.x, mu4.y, mu4.z, mu4.w};
  const float sdr[4] = {sd4.x, sd4.y, sd4.z, sd4.w};
#pragma unroll
  for (int i = 0; i < 8; ++i) {
    int row = mBase + ty * 8 + i;
    float o0, o1, o2, o3;
#define VOUT(j, dst) { \
      int col = nBase + tx * 4 + j; \
      float m_v = acc[i][j] + mur[j]; \
      uint32_t idx = (uint32_t)row * (uint32_t)N + (uint32_t)col; \
      float f = jax_uniform01(kn0, kn1, idx); \
      float u = fmaxf(LO, fmaf(f, 2.0f, LO)); \
      float nz = SQRT2 * erfinv_xla(u); \
      dst = m_v + nz * sdr[j]; }
    VOUT(0, o0) VOUT(1, o1) VOUT(2, o2) VOUT(3, o3)
#undef VOUT
    float4 s = {o0, o1, o2, o3};
    *reinterpret_cast<float4*>(&Vout[(size_t)row * N + nBase + tx * 4]) = s;
  }
}

extern "C" void kernel_launch(void* const* d_in, const int* in_sizes, int n_in,
                              void* d_out, int out_size, void* d_ws, size_t ws_size,
                              hipStream_t stream) {
  const int B = 4096, V = 3072, NUM_STEPS = 8;
  const float* v_in    = (const float*)d_in[0];
  const float* W       = (const float*)d_in[1];
  const float* b       = (const float*)d_in[2];
  const float* mu      = (const float*)d_in[3];
  const float* log_var = (const float*)d_in[4];
  float* out = (float*)d_out;

  float* invvar = (float*)d_ws;
  float* stdv   = invvar + V;
  uint8_t* h    = (uint8_t*)(stdv + V);   // B*H = 2 MiB

  uint32_t k0a, k0b, kl0, kl1;
  threefry2x32(0u, 42u, 0u, 0u, k0a, k0b);
  threefry2x32(0u, 42u, 0u, 1u, kl0, kl1);
  uint32_t kn0[NUM_STEPS], kn1[NUM_STEPS], kb0[NUM_STEPS], kb1[NUM_STEPS];
  for (int t = 0; t < NUM_STEPS; ++t) {
    uint32_t kt0, kt1;
    threefry2x32(kl0, kl1, 0u, (uint32_t)t, kt0, kt1);
    threefry2x32(kt0, kt1, 0u, 0u, kn0[t], kn1[t]);
    threefry2x32(kt0, kt1, 0u, 1u, kb0[t], kb1[t]);
  }

  prep_kernel<<<(V + 255) / 256, 256, 0, stream>>>(log_var, invvar, stdv, V);

  dim3 gridL(256);                 // (N/64)*(M/128) = 8*32
  dim3 gridV(V / 64, B / 128);     // (48, 32)

  gemm_logit_bern<<<gridL, 256, 0, stream>>>(v_in, W, b, invvar, h, k0a, k0b);

  for (int t = 0; t < NUM_STEPS; ++t) {
    float* vt = out + (size_t)t * B * V;
    gemm_v_sample<<<gridV, 256, 0, stream>>>(h, W, mu, stdv, vt, kn0[t], kn1[t]);
    if (t < NUM_STEPS - 1) {
      gemm_logit_bern<<<gridL, 256, 0, stream>>>(vt, W, b, invvar, h, kb0[t], kb1[t]);
    }
  }
}

// Round 7
// 3320.162 us; speedup vs baseline: 1.1795x; 1.1795x over previous
//
#include <hip/hip_runtime.h>
#include <stdint.h>
#include <stddef.h>

// ---------------------------------------------------------------------------
// GRBM Gibbs sampling, round 7. Exact JAX threefry numerics — every output
// keeps ONE ascending-k fmaf chain -> absmax must stay exactly 0.1015625.
// R6 post-mortem: 128x64 L tiling -> grid 256 -> 1 block/CU -> barrier drain
// exposed (VALUBusy 48%, wall 2x). Empirical law: need >=2 blocks/CU.
// R7 = combine proven best: L from R5 (64x64/4x4/KT32/1-barrier/grid512,
// 157us), V from R4 (128x64/8x4/KT16/2-barrier/grid1536, 172us).
// ---------------------------------------------------------------------------

__host__ __device__ inline void threefry2x32(uint32_t k0, uint32_t k1,
                                             uint32_t x0, uint32_t x1,
                                             uint32_t& o0, uint32_t& o1) {
  uint32_t ks2 = k0 ^ k1 ^ 0x1BD11BDAu;
  x0 += k0; x1 += k1;
#define TFR(r) { x0 += x1; x1 = (x1 << (r)) | (x1 >> (32 - (r))); x1 ^= x0; }
  TFR(13) TFR(15) TFR(26) TFR(6)
  x0 += k1;  x1 += ks2 + 1u;
  TFR(17) TFR(29) TFR(16) TFR(24)
  x0 += ks2; x1 += k0 + 2u;
  TFR(13) TFR(15) TFR(26) TFR(6)
  x0 += k0;  x1 += k1 + 3u;
  TFR(17) TFR(29) TFR(16) TFR(24)
  x0 += k1;  x1 += ks2 + 4u;
  TFR(13) TFR(15) TFR(26) TFR(6)
  x0 += ks2; x1 += k0 + 5u;
#undef TFR
  o0 = x0; o1 = x1;
}

__device__ inline float jax_uniform01(uint32_t key0, uint32_t key1, uint32_t idx) {
  uint32_t o0, o1;
  threefry2x32(key0, key1, 0u, idx, o0, o1);
  uint32_t bits = o0 ^ o1;
  return __uint_as_float((bits >> 9) | 0x3f800000u) - 1.0f;
}

__device__ inline float erfinv_xla(float x) {
  float w = -log1pf(-x * x);
  float p;
  if (w < 5.0f) {
    w = w - 2.5f;
    p = 2.81022636e-08f;
    p = fmaf(p, w, 3.43273939e-07f);
    p = fmaf(p, w, -3.5233877e-06f);
    p = fmaf(p, w, -4.39150654e-06f);
    p = fmaf(p, w, 0.00021858087f);
    p = fmaf(p, w, -0.00125372503f);
    p = fmaf(p, w, -0.00417768164f);
    p = fmaf(p, w, 0.246640727f);
    p = fmaf(p, w, 1.50140941f);
  } else {
    w = sqrtf(w) - 3.0f;
    p = -0.000200214257f;
    p = fmaf(p, w, 0.000100950558f);
    p = fmaf(p, w, 0.00134934322f);
    p = fmaf(p, w, -0.00367342844f);
    p = fmaf(p, w, 0.00573950773f);
    p = fmaf(p, w, -0.0076224613f);
    p = fmaf(p, w, 0.00943887047f);
    p = fmaf(p, w, 1.00167406f);
    p = fmaf(p, w, 2.83297682f);
  }
  return p * x;
}

__global__ void prep_kernel(const float* __restrict__ log_var,
                            float* __restrict__ invvar,
                            float* __restrict__ stdv, int V) {
  int i = blockIdx.x * 256 + threadIdx.x;
  if (i < V) {
    float var = fmaxf(expf(log_var[i]), 1e-8f);
    invvar[i] = 1.0f / var;
    stdv[i] = sqrtf(var);
  }
}

// ---------------------------------------------------------------------------
// Kernel L (R5-exact, 157us proven): logits = (Vin*invvar) @ W + b ;
// h = bernoulli(sigmoid(logits)). M=4096, N=512, K=3072.
// BM=64, BN=64, 256 thr, micro 4x4, KT=32, single-barrier dbuf.
// grid=512 (2 blocks/CU); XCD swizzle: xcd=bid&7 owns row-panels.
// ---------------------------------------------------------------------------
__global__ __launch_bounds__(256, 1)
void gemm_logit_bern(const float* __restrict__ Vin, const float* __restrict__ Wm,
                     const float* __restrict__ bias, const float* __restrict__ invvar,
                     uint8_t* __restrict__ Hout, uint32_t kb0, uint32_t kb1) {
  const int N = 512, K = 3072;
  const int KT = 32;
  __shared__ float As[2][KT][68];   // [k][m], +4 pad ; 17.4 KB
  __shared__ float Bs[2][KT][64];   // [k][n]        ; 16.4 KB

  const int tid = threadIdx.x;
  const int bid = blockIdx.x;
  const int xcd = bid & 7;
  const int c = bid >> 3;
  const int mb = xcd * 8 + (c >> 3);
  const int nb = c & 7;
  const int mBase = mb * 64, nBase = nb * 64;

  const int tx = tid & 15, ty = tid >> 4;
  const int am = tid >> 2;               // 0..63
  const int ak = (tid & 3) * 4;          // 0,4,8,12  (+16 for hi half)
  const int bk = tid >> 4;               // 0..15     (+16 for hi half)
  const int bn = (tid & 15) * 4;         // 0..60

  float acc[4][4] = {};

  float4 ra0, ra1, riv0, riv1, rb0, rb1;

#define LOADL(t) { \
  int k0 = (t) * KT; \
  ra0  = *reinterpret_cast<const float4*>(&Vin[(size_t)(mBase + am) * K + k0 + ak]); \
  ra1  = *reinterpret_cast<const float4*>(&Vin[(size_t)(mBase + am) * K + k0 + 16 + ak]); \
  riv0 = *reinterpret_cast<const float4*>(&invvar[k0 + ak]); \
  riv1 = *reinterpret_cast<const float4*>(&invvar[k0 + 16 + ak]); \
  rb0  = *reinterpret_cast<const float4*>(&Wm[(size_t)(k0 + bk) * N + nBase + bn]); \
  rb1  = *reinterpret_cast<const float4*>(&Wm[(size_t)(k0 + 16 + bk) * N + nBase + bn]); }

#define STOREL(p) { \
  As[p][ak + 0][am]      = ra0.x * riv0.x; \
  As[p][ak + 1][am]      = ra0.y * riv0.y; \
  As[p][ak + 2][am]      = ra0.z * riv0.z; \
  As[p][ak + 3][am]      = ra0.w * riv0.w; \
  As[p][ak + 16][am]     = ra1.x * riv1.x; \
  As[p][ak + 17][am]     = ra1.y * riv1.y; \
  As[p][ak + 18][am]     = ra1.z * riv1.z; \
  As[p][ak + 19][am]     = ra1.w * riv1.w; \
  *reinterpret_cast<float4*>(&Bs[p][bk][bn])      = rb0; \
  *reinterpret_cast<float4*>(&Bs[p][bk + 16][bn]) = rb1; }

  LOADL(0)

  int p = 0;
  const int NT = K / KT;   // 96
  for (int t = 0; t < NT; ++t) {
    STOREL(p)
    if (t + 1 < NT) LOADL(t + 1)
    __syncthreads();
#pragma unroll
    for (int kk = 0; kk < KT; ++kk) {
      float4 x = *reinterpret_cast<const float4*>(&As[p][kk][ty * 4]);
      float4 y = *reinterpret_cast<const float4*>(&Bs[p][kk][tx * 4]);
#define LROW(i, a) \
      acc[i][0] = fmaf(a, y.x, acc[i][0]); \
      acc[i][1] = fmaf(a, y.y, acc[i][1]); \
      acc[i][2] = fmaf(a, y.z, acc[i][2]); \
      acc[i][3] = fmaf(a, y.w, acc[i][3]);
      LROW(0, x.x) LROW(1, x.y) LROW(2, x.z) LROW(3, x.w)
#undef LROW
    }
    p ^= 1;
  }
#undef LOADL
#undef STOREL

#pragma unroll
  for (int i = 0; i < 4; ++i) {
    int row = mBase + ty * 4 + i;
    uint32_t hp = 0;
#pragma unroll
    for (int j = 0; j < 4; ++j) {
      int col = nBase + tx * 4 + j;
      float logit = acc[i][j] + bias[col];
      float p2 = 0.5f + 0.5f * tanhf(0.5f * logit);
      uint32_t idx = (uint32_t)row * (uint32_t)N + (uint32_t)col;
      float u = jax_uniform01(kb0, kb1, idx);
      hp |= ((u < p2) ? 1u : 0u) << (8 * j);
    }
    *reinterpret_cast<uint32_t*>(&Hout[(size_t)row * N + nBase + tx * 4]) = hp;
  }
}

// ---------------------------------------------------------------------------
// Kernel V (R4-exact, 172us proven): v = h @ W^T + mu + normal*std.
// M=4096, N=3072, K=512. BM=128, BN=64, 256 thr, micro 8x4, KT=16,
// 2-barrier dbuf. grid=(48,32) -> 6 blocks/CU.
// ---------------------------------------------------------------------------
__global__ __launch_bounds__(256, 2)
void gemm_v_sample(const uint8_t* __restrict__ Hin, const float* __restrict__ Wm,
                   const float* __restrict__ muv, const float* __restrict__ stdv,
                   float* __restrict__ Vout, uint32_t kn0, uint32_t kn1) {
  const int N = 3072, K = 512;
  const int KT = 16;
  __shared__ float As[2][KT][132];   // [k][m 0..127]
  __shared__ float Bs[2][KT][68];    // [k][n 0..63]

  const int tid = threadIdx.x;
  const int mBase = blockIdx.y * 128, nBase = blockIdx.x * 64;
  const int tx = tid & 15, ty = tid >> 4;

  const int am = tid >> 1;               // 0..127
  const int ah = (tid & 1) * 8;          // 0,8
  const int bn = tid >> 2;               // 0..63
  const int bq = (tid & 3) * 4;          // 0,4,8,12

  float acc[8][4] = {};

  uint32_t rh0, rh1;
  float4 rb;
  {
    const uint32_t* hp_ = reinterpret_cast<const uint32_t*>(&Hin[(size_t)(mBase + am) * K + ah]);
    rh0 = hp_[0]; rh1 = hp_[1];
  }
  rb = *reinterpret_cast<const float4*>(&Wm[(size_t)(nBase + bn) * K + bq]);

#define STAGE_V(buf) { \
  As[buf][ah + 0][am] = (float)((rh0 >> 0) & 0xffu); \
  As[buf][ah + 1][am] = (float)((rh0 >> 8) & 0xffu); \
  As[buf][ah + 2][am] = (float)((rh0 >> 16) & 0xffu); \
  As[buf][ah + 3][am] = (float)((rh0 >> 24) & 0xffu); \
  As[buf][ah + 4][am] = (float)((rh1 >> 0) & 0xffu); \
  As[buf][ah + 5][am] = (float)((rh1 >> 8) & 0xffu); \
  As[buf][ah + 6][am] = (float)((rh1 >> 16) & 0xffu); \
  As[buf][ah + 7][am] = (float)((rh1 >> 24) & 0xffu); \
  Bs[buf][bq + 0][bn] = rb.x; \
  Bs[buf][bq + 1][bn] = rb.y; \
  Bs[buf][bq + 2][bn] = rb.z; \
  Bs[buf][bq + 3][bn] = rb.w; }

  STAGE_V(0)
  __syncthreads();

  int cur = 0;
  const int NT = K / KT;   // 32
  for (int t = 0; t < NT; ++t) {
    const bool more = (t + 1 < NT);
    if (more) {
      int k0 = (t + 1) * KT;
      const uint32_t* hp_ = reinterpret_cast<const uint32_t*>(&Hin[(size_t)(mBase + am) * K + k0 + ah]);
      rh0 = hp_[0]; rh1 = hp_[1];
      rb = *reinterpret_cast<const float4*>(&Wm[(size_t)(nBase + bn) * K + k0 + bq]);
    }
#pragma unroll
    for (int kk = 0; kk < KT; ++kk) {
      float4 x0 = *reinterpret_cast<const float4*>(&As[cur][kk][ty * 8]);
      float4 x1 = *reinterpret_cast<const float4*>(&As[cur][kk][ty * 8 + 4]);
      float4 y  = *reinterpret_cast<const float4*>(&Bs[cur][kk][tx * 4]);
#define VROW(i, a) \
      acc[i][0] = fmaf(a, y.x, acc[i][0]); \
      acc[i][1] = fmaf(a, y.y, acc[i][1]); \
      acc[i][2] = fmaf(a, y.z, acc[i][2]); \
      acc[i][3] = fmaf(a, y.w, acc[i][3]);
      VROW(0, x0.x) VROW(1, x0.y) VROW(2, x0.z) VROW(3, x0.w)
      VROW(4, x1.x) VROW(5, x1.y) VROW(6, x1.z) VROW(7, x1.w)
#undef VROW
    }
    if (more) {
      __syncthreads();
      STAGE_V(cur ^ 1)
      __syncthreads();
      cur ^= 1;
    }
  }
#undef STAGE_V

  const float LO = -0.99999994f;
  const float SQRT2 = 1.41421356237f;
  const float4 mu4 = *reinterpret_cast<const float4*>(&muv[nBase + tx * 4]);
  const float4 sd4 = *reinterpret_cast<const float4*>(&stdv[nBase + tx * 4]);
  const float mur[4] = {mu4.x, mu4.y, mu4.z, mu4.w};
  const float sdr[4] = {sd4.x, sd4.y, sd4.z, sd4.w};
#pragma unroll
  for (int i = 0; i < 8; ++i) {
    int row = mBase + ty * 8 + i;
    float o0, o1, o2, o3;
#define VOUT(j, dst) { \
      int col = nBase + tx * 4 + j; \
      float m_v = acc[i][j] + mur[j]; \
      uint32_t idx = (uint32_t)row * (uint32_t)N + (uint32_t)col; \
      float f = jax_uniform01(kn0, kn1, idx); \
      float u = fmaxf(LO, fmaf(f, 2.0f, LO)); \
      float nz = SQRT2 * erfinv_xla(u); \
      dst = m_v + nz * sdr[j]; }
    VOUT(0, o0) VOUT(1, o1) VOUT(2, o2) VOUT(3, o3)
#undef VOUT
    float4 s = {o0, o1, o2, o3};
    *reinterpret_cast<float4*>(&Vout[(size_t)row * N + nBase + tx * 4]) = s;
  }
}

extern "C" void kernel_launch(void* const* d_in, const int* in_sizes, int n_in,
                              void* d_out, int out_size, void* d_ws, size_t ws_size,
                              hipStream_t stream) {
  const int B = 4096, V = 3072, NUM_STEPS = 8;
  const float* v_in    = (const float*)d_in[0];
  const float* W       = (const float*)d_in[1];
  const float* b       = (const float*)d_in[2];
  const float* mu      = (const float*)d_in[3];
  const float* log_var = (const float*)d_in[4];
  float* out = (float*)d_out;

  float* invvar = (float*)d_ws;
  float* stdv   = invvar + V;
  uint8_t* h    = (uint8_t*)(stdv + V);   // B*H = 2 MiB

  uint32_t k0a, k0b, kl0, kl1;
  threefry2x32(0u, 42u, 0u, 0u, k0a, k0b);
  threefry2x32(0u, 42u, 0u, 1u, kl0, kl1);
  uint32_t kn0[NUM_STEPS], kn1[NUM_STEPS], kb0[NUM_STEPS], kb1[NUM_STEPS];
  for (int t = 0; t < NUM_STEPS; ++t) {
    uint32_t kt0, kt1;
    threefry2x32(kl0, kl1, 0u, (uint32_t)t, kt0, kt1);
    threefry2x32(kt0, kt1, 0u, 0u, kn0[t], kn1[t]);
    threefry2x32(kt0, kt1, 0u, 1u, kb0[t], kb1[t]);
  }

  prep_kernel<<<(V + 255) / 256, 256, 0, stream>>>(log_var, invvar, stdv, V);

  dim3 gridL(512);                 // (M/64)*(N/64) = 64*8, XCD-swizzled
  dim3 gridV(V / 64, B / 128);     // (48, 32)

  gemm_logit_bern<<<gridL, 256, 0, stream>>>(v_in, W, b, invvar, h, k0a, k0b);

  for (int t = 0; t < NUM_STEPS; ++t) {
    float* vt = out + (size_t)t * B * V;
    gemm_v_sample<<<gridV, 256, 0, stream>>>(h, W, mu, stdv, vt, kn0[t], kn1[t]);
    if (t < NUM_STEPS - 1) {
      gemm_logit_bern<<<gridL, 256, 0, stream>>>(vt, W, b, invvar, h, kb0[t], kb1[t]);
    }
  }
}

// Round 8
// 2397.652 us; speedup vs baseline: 1.6334x; 1.3848x over previous
//
#include <hip/hip_runtime.h>
#include <stdint.h>
#include <stddef.h>

// ---------------------------------------------------------------------------
// GRBM Gibbs sampling, round 8.
// V kernel moved to MFMA (bf16 3-way error-free split of W; h is bf16-exact).
// Accumulation-order changes re-roll Bernoulli boundary draws -> absmax is a
// fresh draw (~0.1 scale expected). L kernel = R7-exact fp32 (proven 159us).
// W-splits precomputed in d_ws (11.6 MB, gated on ws_size; fallback = R7 V).
// A/B fragment staging uses the same (lanegroup,elem)->k bijection for both
// operands, so the HW's internal k-order cancels. C/D: col=lane&15,
// row=(lane>>4)*4+reg (verified mapping).
// ---------------------------------------------------------------------------

typedef __attribute__((ext_vector_type(8))) __bf16 bf16x8;
typedef __attribute__((ext_vector_type(4))) float f32x4;

__host__ __device__ inline void threefry2x32(uint32_t k0, uint32_t k1,
                                             uint32_t x0, uint32_t x1,
                                             uint32_t& o0, uint32_t& o1) {
  uint32_t ks2 = k0 ^ k1 ^ 0x1BD11BDAu;
  x0 += k0; x1 += k1;
#define TFR(r) { x0 += x1; x1 = (x1 << (r)) | (x1 >> (32 - (r))); x1 ^= x0; }
  TFR(13) TFR(15) TFR(26) TFR(6)
  x0 += k1;  x1 += ks2 + 1u;
  TFR(17) TFR(29) TFR(16) TFR(24)
  x0 += ks2; x1 += k0 + 2u;
  TFR(13) TFR(15) TFR(26) TFR(6)
  x0 += k0;  x1 += k1 + 3u;
  TFR(17) TFR(29) TFR(16) TFR(24)
  x0 += k1;  x1 += ks2 + 4u;
  TFR(13) TFR(15) TFR(26) TFR(6)
  x0 += ks2; x1 += k0 + 5u;
#undef TFR
  o0 = x0; o1 = x1;
}

__device__ inline float jax_uniform01(uint32_t key0, uint32_t key1, uint32_t idx) {
  uint32_t o0, o1;
  threefry2x32(key0, key1, 0u, idx, o0, o1);
  uint32_t bits = o0 ^ o1;
  return __uint_as_float((bits >> 9) | 0x3f800000u) - 1.0f;
}

__device__ inline float erfinv_xla(float x) {
  float w = -log1pf(-x * x);
  float p;
  if (w < 5.0f) {
    w = w - 2.5f;
    p = 2.81022636e-08f;
    p = fmaf(p, w, 3.43273939e-07f);
    p = fmaf(p, w, -3.5233877e-06f);
    p = fmaf(p, w, -4.39150654e-06f);
    p = fmaf(p, w, 0.00021858087f);
    p = fmaf(p, w, -0.00125372503f);
    p = fmaf(p, w, -0.00417768164f);
    p = fmaf(p, w, 0.246640727f);
    p = fmaf(p, w, 1.50140941f);
  } else {
    w = sqrtf(w) - 3.0f;
    p = -0.000200214257f;
    p = fmaf(p, w, 0.000100950558f);
    p = fmaf(p, w, 0.00134934322f);
    p = fmaf(p, w, -0.00367342844f);
    p = fmaf(p, w, 0.00573950773f);
    p = fmaf(p, w, -0.0076224613f);
    p = fmaf(p, w, 0.00943887047f);
    p = fmaf(p, w, 1.00167406f);
    p = fmaf(p, w, 2.83297682f);
  }
  return p * x;
}

__global__ void prep_kernel(const float* __restrict__ log_var,
                            float* __restrict__ invvar,
                            float* __restrict__ stdv, int V) {
  int i = blockIdx.x * 256 + threadIdx.x;
  if (i < V) {
    float var = fmaxf(expf(log_var[i]), 1e-8f);
    invvar[i] = 1.0f / var;
    stdv[i] = sqrtf(var);
  }
}

// RTN-even f32 -> bf16 bits; also returns the bf16 value back in f32.
__device__ inline unsigned short rtn_bf16(float x, float& back) {
  uint32_t u = __float_as_uint(x);
  uint32_t r = u + 0x7fffu + ((u >> 16) & 1u);
  unsigned short s = (unsigned short)(r >> 16);
  back = __uint_as_float(((uint32_t)s) << 16);
  return s;
}

// Split W (1572864 f32) into 3 bf16 planes: w = w0 + w1 + w2 (error ~2^-25 rel)
__global__ __launch_bounds__(256)
void split_w_kernel(const float* __restrict__ W,
                    unsigned short* __restrict__ P0,
                    unsigned short* __restrict__ P1,
                    unsigned short* __restrict__ P2) {
  int gid = blockIdx.x * 256 + threadIdx.x;   // 0..393215
  int base = gid * 4;
  float4 x = *reinterpret_cast<const float4*>(&W[base]);
  ushort4 a0, a1, a2;
  float b, r1, r2;
  {
    a0.x = rtn_bf16(x.x, b); r1 = x.x - b;
    a1.x = rtn_bf16(r1, b);  r2 = r1 - b;
    a2.x = rtn_bf16(r2, b);
  }
  {
    a0.y = rtn_bf16(x.y, b); r1 = x.y - b;
    a1.y = rtn_bf16(r1, b);  r2 = r1 - b;
    a2.y = rtn_bf16(r2, b);
  }
  {
    a0.z = rtn_bf16(x.z, b); r1 = x.z - b;
    a1.z = rtn_bf16(r1, b);  r2 = r1 - b;
    a2.z = rtn_bf16(r2, b);
  }
  {
    a0.w = rtn_bf16(x.w, b); r1 = x.w - b;
    a1.w = rtn_bf16(r1, b);  r2 = r1 - b;
    a2.w = rtn_bf16(r2, b);
  }
  *reinterpret_cast<ushort4*>(&P0[base]) = a0;
  *reinterpret_cast<ushort4*>(&P1[base]) = a1;
  *reinterpret_cast<ushort4*>(&P2[base]) = a2;
}

// ---------------------------------------------------------------------------
// Kernel L (R7-exact): logits = (Vin*invvar) @ W + b ; h = bern(sigmoid).
// BM=64, BN=64, micro 4x4, KT=32, 1-barrier dbuf, grid=512, XCD swizzle.
// ---------------------------------------------------------------------------
__global__ __launch_bounds__(256, 1)
void gemm_logit_bern(const float* __restrict__ Vin, const float* __restrict__ Wm,
                     const float* __restrict__ bias, const float* __restrict__ invvar,
                     uint8_t* __restrict__ Hout, uint32_t kb0, uint32_t kb1) {
  const int N = 512, K = 3072;
  const int KT = 32;
  __shared__ float As[2][KT][68];
  __shared__ float Bs[2][KT][64];

  const int tid = threadIdx.x;
  const int bid = blockIdx.x;
  const int xcd = bid & 7;
  const int c = bid >> 3;
  const int mb = xcd * 8 + (c >> 3);
  const int nb = c & 7;
  const int mBase = mb * 64, nBase = nb * 64;

  const int tx = tid & 15, ty = tid >> 4;
  const int am = tid >> 2;
  const int ak = (tid & 3) * 4;
  const int bk = tid >> 4;
  const int bn = (tid & 15) * 4;

  float acc[4][4] = {};

  float4 ra0, ra1, riv0, riv1, rb0, rb1;

#define LOADL(t) { \
  int k0 = (t) * KT; \
  ra0  = *reinterpret_cast<const float4*>(&Vin[(size_t)(mBase + am) * K + k0 + ak]); \
  ra1  = *reinterpret_cast<const float4*>(&Vin[(size_t)(mBase + am) * K + k0 + 16 + ak]); \
  riv0 = *reinterpret_cast<const float4*>(&invvar[k0 + ak]); \
  riv1 = *reinterpret_cast<const float4*>(&invvar[k0 + 16 + ak]); \
  rb0  = *reinterpret_cast<const float4*>(&Wm[(size_t)(k0 + bk) * N + nBase + bn]); \
  rb1  = *reinterpret_cast<const float4*>(&Wm[(size_t)(k0 + 16 + bk) * N + nBase + bn]); }

#define STOREL(p) { \
  As[p][ak + 0][am]      = ra0.x * riv0.x; \
  As[p][ak + 1][am]      = ra0.y * riv0.y; \
  As[p][ak + 2][am]      = ra0.z * riv0.z; \
  As[p][ak + 3][am]      = ra0.w * riv0.w; \
  As[p][ak + 16][am]     = ra1.x * riv1.x; \
  As[p][ak + 17][am]     = ra1.y * riv1.y; \
  As[p][ak + 18][am]     = ra1.z * riv1.z; \
  As[p][ak + 19][am]     = ra1.w * riv1.w; \
  *reinterpret_cast<float4*>(&Bs[p][bk][bn])      = rb0; \
  *reinterpret_cast<float4*>(&Bs[p][bk + 16][bn]) = rb1; }

  LOADL(0)

  int p = 0;
  const int NT = K / KT;   // 96
  for (int t = 0; t < NT; ++t) {
    STOREL(p)
    if (t + 1 < NT) LOADL(t + 1)
    __syncthreads();
#pragma unroll
    for (int kk = 0; kk < KT; ++kk) {
      float4 x = *reinterpret_cast<const float4*>(&As[p][kk][ty * 4]);
      float4 y = *reinterpret_cast<const float4*>(&Bs[p][kk][tx * 4]);
#define LROW(i, a) \
      acc[i][0] = fmaf(a, y.x, acc[i][0]); \
      acc[i][1] = fmaf(a, y.y, acc[i][1]); \
      acc[i][2] = fmaf(a, y.z, acc[i][2]); \
      acc[i][3] = fmaf(a, y.w, acc[i][3]);
      LROW(0, x.x) LROW(1, x.y) LROW(2, x.z) LROW(3, x.w)
#undef LROW
    }
    p ^= 1;
  }
#undef LOADL
#undef STOREL

#pragma unroll
  for (int i = 0; i < 4; ++i) {
    int row = mBase + ty * 4 + i;
    uint32_t hp = 0;
#pragma unroll
    for (int j = 0; j < 4; ++j) {
      int col = nBase + tx * 4 + j;
      float logit = acc[i][j] + bias[col];
      float p2 = 0.5f + 0.5f * tanhf(0.5f * logit);
      uint32_t idx = (uint32_t)row * (uint32_t)N + (uint32_t)col;
      float u = jax_uniform01(kb0, kb1, idx);
      hp |= ((u < p2) ? 1u : 0u) << (8 * j);
    }
    *reinterpret_cast<uint32_t*>(&Hout[(size_t)row * N + nBase + tx * 4]) = hp;
  }
}

// ---------------------------------------------------------------------------
// Kernel V-MFMA: v = h @ W^T + mu + normal*std.  M=4096, N=3072, K=512.
// BM=BN=64, 4 waves (2x2, each 32x32), KT=32, 2-barrier dbuf.
// 3 MFMA passes (W planes hi/mid/lo); h exact in bf16.
// A-frag: lane 16g+m, elems j=0..7  <- As[m][8g+j]
// B-frag: lane 16g+n, elems j=0..7  <- Bs[n][8g+j]   (same k bijection)
// C/D: col=lane&15, row=(lane>>4)*4+reg.
// LDS rows padded to 40 shorts (80B) -> frag reads ~2-way conflict (free).
// ---------------------------------------------------------------------------
__global__ __launch_bounds__(256, 1)
void gemm_v_mfma(const uint8_t* __restrict__ Hin,
                 const unsigned short* __restrict__ W0,
                 const unsigned short* __restrict__ W1,
                 const unsigned short* __restrict__ W2,
                 const float* __restrict__ muv, const float* __restrict__ stdv,
                 float* __restrict__ Vout, uint32_t kn0, uint32_t kn1) {
  const int N = 3072, K = 512;
  __shared__ __attribute__((aligned(16))) unsigned short As[2][64][40];
  __shared__ __attribute__((aligned(16))) unsigned short Bs[2][3][64][40];

  const int tid = threadIdx.x;
  const int mBase = blockIdx.y * 64, nBase = blockIdx.x * 64;
  const int lane = tid & 63, w = tid >> 6;
  const int wr = w >> 1, wc = w & 1;          // wave -> 32x32 quadrant
  const int lg = lane >> 4, lm = lane & 15;

  const int srow = tid >> 2;        // 0..63 (staging row)
  const int soff = (tid & 3) * 8;   // 0,8,16,24 (staging k-offset)

  f32x4 acc00 = {0.f, 0.f, 0.f, 0.f};
  f32x4 acc01 = {0.f, 0.f, 0.f, 0.f};
  f32x4 acc10 = {0.f, 0.f, 0.f, 0.f};
  f32x4 acc11 = {0.f, 0.f, 0.f, 0.f};

  const __bf16 ONE = (__bf16)1.0f;
  const __bf16 ZERO = (__bf16)0.0f;

  uint64_t rh;
  bf16x8 rw0, rw1, rw2;

#define LOADV(t) { \
  int k0 = (t) * 32; \
  rh  = *reinterpret_cast<const uint64_t*>(&Hin[(size_t)(mBase + srow) * K + k0 + soff]); \
  rw0 = *reinterpret_cast<const bf16x8*>(&W0[(size_t)(nBase + srow) * K + k0 + soff]); \
  rw1 = *reinterpret_cast<const bf16x8*>(&W1[(size_t)(nBase + srow) * K + k0 + soff]); \
  rw2 = *reinterpret_cast<const bf16x8*>(&W2[(size_t)(nBase + srow) * K + k0 + soff]); }

#define STAGEV(p) { \
  bf16x8 hv; \
  hv[0] = ((rh >> 0)  & 0xffu) ? ONE : ZERO; \
  hv[1] = ((rh >> 8)  & 0xffu) ? ONE : ZERO; \
  hv[2] = ((rh >> 16) & 0xffu) ? ONE : ZERO; \
  hv[3] = ((rh >> 24) & 0xffu) ? ONE : ZERO; \
  hv[4] = ((rh >> 32) & 0xffu) ? ONE : ZERO; \
  hv[5] = ((rh >> 40) & 0xffu) ? ONE : ZERO; \
  hv[6] = ((rh >> 48) & 0xffu) ? ONE : ZERO; \
  hv[7] = ((rh >> 56) & 0xffu) ? ONE : ZERO; \
  *reinterpret_cast<bf16x8*>(&As[p][srow][soff])    = hv; \
  *reinterpret_cast<bf16x8*>(&Bs[p][0][srow][soff]) = rw0; \
  *reinterpret_cast<bf16x8*>(&Bs[p][1][srow][soff]) = rw1; \
  *reinterpret_cast<bf16x8*>(&Bs[p][2][srow][soff]) = rw2; }

  LOADV(0)
  STAGEV(0)
  __syncthreads();

  int cur = 0;
  const int NT = K / 32;   // 16
  for (int t = 0; t < NT; ++t) {
    const bool more = (t + 1 < NT);
    if (more) LOADV(t + 1)

    bf16x8 a0 = *reinterpret_cast<const bf16x8*>(&As[cur][wr * 32 + lm][lg * 8]);
    bf16x8 a1 = *reinterpret_cast<const bf16x8*>(&As[cur][wr * 32 + 16 + lm][lg * 8]);
    bf16x8 b00 = *reinterpret_cast<const bf16x8*>(&Bs[cur][0][wc * 32 + lm][lg * 8]);
    bf16x8 b01 = *reinterpret_cast<const bf16x8*>(&Bs[cur][0][wc * 32 + 16 + lm][lg * 8]);
    bf16x8 b10 = *reinterpret_cast<const bf16x8*>(&Bs[cur][1][wc * 32 + lm][lg * 8]);
    bf16x8 b11 = *reinterpret_cast<const bf16x8*>(&Bs[cur][1][wc * 32 + 16 + lm][lg * 8]);
    bf16x8 b20 = *reinterpret_cast<const bf16x8*>(&Bs[cur][2][wc * 32 + lm][lg * 8]);
    bf16x8 b21 = *reinterpret_cast<const bf16x8*>(&Bs[cur][2][wc * 32 + 16 + lm][lg * 8]);

    acc00 = __builtin_amdgcn_mfma_f32_16x16x32_bf16(a0, b00, acc00, 0, 0, 0);
    acc01 = __builtin_amdgcn_mfma_f32_16x16x32_bf16(a0, b01, acc01, 0, 0, 0);
    acc10 = __builtin_amdgcn_mfma_f32_16x16x32_bf16(a1, b00, acc10, 0, 0, 0);
    acc11 = __builtin_amdgcn_mfma_f32_16x16x32_bf16(a1, b01, acc11, 0, 0, 0);
    acc00 = __builtin_amdgcn_mfma_f32_16x16x32_bf16(a0, b10, acc00, 0, 0, 0);
    acc01 = __builtin_amdgcn_mfma_f32_16x16x32_bf16(a0, b11, acc01, 0, 0, 0);
    acc10 = __builtin_amdgcn_mfma_f32_16x16x32_bf16(a1, b10, acc10, 0, 0, 0);
    acc11 = __builtin_amdgcn_mfma_f32_16x16x32_bf16(a1, b11, acc11, 0, 0, 0);
    acc00 = __builtin_amdgcn_mfma_f32_16x16x32_bf16(a0, b20, acc00, 0, 0, 0);
    acc01 = __builtin_amdgcn_mfma_f32_16x16x32_bf16(a0, b21, acc01, 0, 0, 0);
    acc10 = __builtin_amdgcn_mfma_f32_16x16x32_bf16(a1, b20, acc10, 0, 0, 0);
    acc11 = __builtin_amdgcn_mfma_f32_16x16x32_bf16(a1, b21, acc11, 0, 0, 0);

    if (more) {
      __syncthreads();
      STAGEV(cur ^ 1)
      __syncthreads();
      cur ^= 1;
    }
  }
#undef LOADV
#undef STAGEV

  const float LO = -0.99999994f;
  const float SQRT2 = 1.41421356237f;
  const int col0 = nBase + wc * 32 + lm;
  const int col1 = col0 + 16;
  const float mu0 = muv[col0], mu1 = muv[col1];
  const float sd0 = stdv[col0], sd1 = stdv[col1];

#define VOUTM(accv, r, rowv, colv, muvv, sdvv) { \
  int row = (rowv); int col = (colv); \
  float m_v = accv[r] + (muvv); \
  uint32_t idx = (uint32_t)row * (uint32_t)N + (uint32_t)col; \
  float f = jax_uniform01(kn0, kn1, idx); \
  float u = fmaxf(LO, fmaf(f, 2.0f, LO)); \
  float nz = SQRT2 * erfinv_xla(u); \
  Vout[(size_t)row * N + col] = m_v + nz * (sdvv); }

#pragma unroll
  for (int r = 0; r < 4; ++r) {
    int row0 = mBase + wr * 32 + lg * 4 + r;
    int row1 = row0 + 16;
    VOUTM(acc00, r, row0, col0, mu0, sd0)
    VOUTM(acc01, r, row0, col1, mu1, sd1)
    VOUTM(acc10, r, row1, col0, mu0, sd0)
    VOUTM(acc11, r, row1, col1, mu1, sd1)
  }
#undef VOUTM
}

// ---------------------------------------------------------------------------
// Kernel V fallback (R7-exact fp32) — used when ws_size is too small for the
// W split planes.
// ---------------------------------------------------------------------------
__global__ __launch_bounds__(256, 2)
void gemm_v_sample(const uint8_t* __restrict__ Hin, const float* __restrict__ Wm,
                   const float* __restrict__ muv, const float* __restrict__ stdv,
                   float* __restrict__ Vout, uint32_t kn0, uint32_t kn1) {
  const int N = 3072, K = 512;
  const int KT = 16;
  __shared__ float As[2][KT][132];
  __shared__ float Bs[2][KT][68];

  const int tid = threadIdx.x;
  const int mBase = blockIdx.y * 128, nBase = blockIdx.x * 64;
  const int tx = tid & 15, ty = tid >> 4;

  const int am = tid >> 1;
  const int ah = (tid & 1) * 8;
  const int bn = tid >> 2;
  const int bq = (tid & 3) * 4;

  float acc[8][4] = {};

  uint32_t rh0, rh1;
  float4 rb;
  {
    const uint32_t* hp_ = reinterpret_cast<const uint32_t*>(&Hin[(size_t)(mBase + am) * K + ah]);
    rh0 = hp_[0]; rh1 = hp_[1];
  }
  rb = *reinterpret_cast<const float4*>(&Wm[(size_t)(nBase + bn) * K + bq]);

#define STAGE_V(buf) { \
  As[buf][ah + 0][am] = (float)((rh0 >> 0) & 0xffu); \
  As[buf][ah + 1][am] = (float)((rh0 >> 8) & 0xffu); \
  As[buf][ah + 2][am] = (float)((rh0 >> 16) & 0xffu); \
  As[buf][ah + 3][am] = (float)((rh0 >> 24) & 0xffu); \
  As[buf][ah + 4][am] = (float)((rh1 >> 0) & 0xffu); \
  As[buf][ah + 5][am] = (float)((rh1 >> 8) & 0xffu); \
  As[buf][ah + 6][am] = (float)((rh1 >> 16) & 0xffu); \
  As[buf][ah + 7][am] = (float)((rh1 >> 24) & 0xffu); \
  Bs[buf][bq + 0][bn] = rb.x; \
  Bs[buf][bq + 1][bn] = rb.y; \
  Bs[buf][bq + 2][bn] = rb.z; \
  Bs[buf][bq + 3][bn] = rb.w; }

  STAGE_V(0)
  __syncthreads();

  int cur = 0;
  const int NT = K / KT;
  for (int t = 0; t < NT; ++t) {
    const bool more = (t + 1 < NT);
    if (more) {
      int k0 = (t + 1) * KT;
      const uint32_t* hp_ = reinterpret_cast<const uint32_t*>(&Hin[(size_t)(mBase + am) * K + k0 + ah]);
      rh0 = hp_[0]; rh1 = hp_[1];
      rb = *reinterpret_cast<const float4*>(&Wm[(size_t)(nBase + bn) * K + k0 + bq]);
    }
#pragma unroll
    for (int kk = 0; kk < KT; ++kk) {
      float4 x0 = *reinterpret_cast<const float4*>(&As[cur][kk][ty * 8]);
      float4 x1 = *reinterpret_cast<const float4*>(&As[cur][kk][ty * 8 + 4]);
      float4 y  = *reinterpret_cast<const float4*>(&Bs[cur][kk][tx * 4]);
#define VROW(i, a) \
      acc[i][0] = fmaf(a, y.x, acc[i][0]); \
      acc[i][1] = fmaf(a, y.y, acc[i][1]); \
      acc[i][2] = fmaf(a, y.z, acc[i][2]); \
      acc[i][3] = fmaf(a, y.w, acc[i][3]);
      VROW(0, x0.x) VROW(1, x0.y) VROW(2, x0.z) VROW(3, x0.w)
      VROW(4, x1.x) VROW(5, x1.y) VROW(6, x1.z) VROW(7, x1.w)
#undef VROW
    }
    if (more) {
      __syncthreads();
      STAGE_V(cur ^ 1)
      __syncthreads();
      cur ^= 1;
    }
  }
#undef STAGE_V

  const float LO = -0.99999994f;
  const float SQRT2 = 1.41421356237f;
  const float4 mu4 = *reinterpret_cast<const float4*>(&muv[nBase + tx * 4]);
  const float4 sd4 = *reinterpret_cast<const float4*>(&stdv[nBase + tx * 4]);
  const float mur[4] = {mu4.x, mu4.y, mu4.z, mu4.w};
  const float sdr[4] = {sd4.x, sd4.y, sd4.z, sd4.w};
#pragma unroll
  for (int i = 0; i < 8; ++i) {
    int row = mBase + ty * 8 + i;
    float o0, o1, o2, o3;
#define VOUT(j, dst) { \
      int col = nBase + tx * 4 + j; \
      float m_v = acc[i][j] + mur[j]; \
      uint32_t idx = (uint32_t)row * (uint32_t)N + (uint32_t)col; \
      float f = jax_uniform01(kn0, kn1, idx); \
      float u = fmaxf(LO, fmaf(f, 2.0f, LO)); \
      float nz = SQRT2 * erfinv_xla(u); \
      dst = m_v + nz * sdr[j]; }
    VOUT(0, o0) VOUT(1, o1) VOUT(2, o2) VOUT(3, o3)
#undef VOUT
    float4 s = {o0, o1, o2, o3};
    *reinterpret_cast<float4*>(&Vout[(size_t)row * N + nBase + tx * 4]) = s;
  }
}

extern "C" void kernel_launch(void* const* d_in, const int* in_sizes, int n_in,
                              void* d_out, int out_size, void* d_ws, size_t ws_size,
                              hipStream_t stream) {
  const int B = 4096, V = 3072, H = 512, NUM_STEPS = 8;
  const float* v_in    = (const float*)d_in[0];
  const float* W       = (const float*)d_in[1];
  const float* b       = (const float*)d_in[2];
  const float* mu      = (const float*)d_in[3];
  const float* log_var = (const float*)d_in[4];
  float* out = (float*)d_out;

  // ws layout (MFMA path):
  //   invvar f32[3072] | stdv f32[3072] | W0,W1,W2 u16[1572864] each | h u8[2M]
  const size_t WELEMS = (size_t)V * H;                 // 1572864
  const size_t NEED = 24576 + 3 * WELEMS * 2 + (size_t)B * H;
  const bool use_mfma = (ws_size >= NEED);

  float* invvar = (float*)d_ws;
  float* stdv   = invvar + V;
  unsigned short* W0 = (unsigned short*)(stdv + V);
  unsigned short* W1 = W0 + WELEMS;
  unsigned short* W2 = W1 + WELEMS;
  uint8_t* h;
  if (use_mfma) h = (uint8_t*)(W2 + WELEMS);
  else          h = (uint8_t*)(stdv + V);

  uint32_t k0a, k0b, kl0, kl1;
  threefry2x32(0u, 42u, 0u, 0u, k0a, k0b);
  threefry2x32(0u, 42u, 0u, 1u, kl0, kl1);
  uint32_t kn0[NUM_STEPS], kn1[NUM_STEPS], kb0[NUM_STEPS], kb1[NUM_STEPS];
  for (int t = 0; t < NUM_STEPS; ++t) {
    uint32_t kt0, kt1;
    threefry2x32(kl0, kl1, 0u, (uint32_t)t, kt0, kt1);
    threefry2x32(kt0, kt1, 0u, 0u, kn0[t], kn1[t]);
    threefry2x32(kt0, kt1, 0u, 1u, kb0[t], kb1[t]);
  }

  prep_kernel<<<(V + 255) / 256, 256, 0, stream>>>(log_var, invvar, stdv, V);
  if (use_mfma) {
    split_w_kernel<<<(int)(WELEMS / 4 / 256), 256, 0, stream>>>(W, W0, W1, W2);
  }

  dim3 gridL(512);                  // (M/64)*(N/64), XCD-swizzled
  dim3 gridVm(V / 64, B / 64);      // (48, 64) MFMA path
  dim3 gridVf(V / 64, B / 128);     // (48, 32) fallback

  gemm_logit_bern<<<gridL, 256, 0, stream>>>(v_in, W, b, invvar, h, k0a, k0b);

  for (int t = 0; t < NUM_STEPS; ++t) {
    float* vt = out + (size_t)t * B * V;
    if (use_mfma) {
      gemm_v_mfma<<<gridVm, 256, 0, stream>>>(h, W0, W1, W2, mu, stdv, vt, kn0[t], kn1[t]);
    } else {
      gemm_v_sample<<<gridVf, 256, 0, stream>>>(h, W, mu, stdv, vt, kn0[t], kn1[t]);
    }
    if (t < NUM_STEPS - 1) {
      gemm_logit_bern<<<gridL, 256, 0, stream>>>(vt, W, b, invvar, h, kb0[t], kb1[t]);
    }
  }
}

// Round 9
// 1677.956 us; speedup vs baseline: 2.3339x; 1.4289x over previous
//
#include <hip/hip_runtime.h>
#include <stdint.h>
#include <stddef.h>

// ---------------------------------------------------------------------------
// GRBM Gibbs sampling, round 9. Both GEMMs on MFMA.
//  - V (mu_v = h@W^T): 3 bf16 W-planes (error-free split), h exact. Proven R8.
//    Epilogue now ALSO emits the 3-plane bf16 split of v_new (A-planes).
//  - L (logits = (v/var)@W): invvar folded into W-planes -> A operand is raw
//    v = A0+A1+A2 (exact). B planes = (ivv*W)^T pre-transposed to [n][k].
//    6-pass magnitude-pruned product (error ~2^-25, fp32-chain quality).
// Accumulation-order changes re-roll a few boundary Bernoulli flips ->
// absmax is a fresh ~0.1-scale draw (R8: 0.09375 passed at thr 0.1256).
// ws gating: full path needs ~96.5 MB; falls back to R8 path (11.6 MB), then
// to pure-fp32 R7 path.
// ---------------------------------------------------------------------------

typedef __attribute__((ext_vector_type(8))) __bf16 bf16x8;
typedef __attribute__((ext_vector_type(4))) float f32x4;

__host__ __device__ inline void threefry2x32(uint32_t k0, uint32_t k1,
                                             uint32_t x0, uint32_t x1,
                                             uint32_t& o0, uint32_t& o1) {
  uint32_t ks2 = k0 ^ k1 ^ 0x1BD11BDAu;
  x0 += k0; x1 += k1;
#define TFR(r) { x0 += x1; x1 = (x1 << (r)) | (x1 >> (32 - (r))); x1 ^= x0; }
  TFR(13) TFR(15) TFR(26) TFR(6)
  x0 += k1;  x1 += ks2 + 1u;
  TFR(17) TFR(29) TFR(16) TFR(24)
  x0 += ks2; x1 += k0 + 2u;
  TFR(13) TFR(15) TFR(26) TFR(6)
  x0 += k0;  x1 += k1 + 3u;
  TFR(17) TFR(29) TFR(16) TFR(24)
  x0 += k1;  x1 += ks2 + 4u;
  TFR(13) TFR(15) TFR(26) TFR(6)
  x0 += ks2; x1 += k0 + 5u;
#undef TFR
  o0 = x0; o1 = x1;
}

__device__ inline float jax_uniform01(uint32_t key0, uint32_t key1, uint32_t idx) {
  uint32_t o0, o1;
  threefry2x32(key0, key1, 0u, idx, o0, o1);
  uint32_t bits = o0 ^ o1;
  return __uint_as_float((bits >> 9) | 0x3f800000u) - 1.0f;
}

__device__ inline float erfinv_xla(float x) {
  float w = -log1pf(-x * x);
  float p;
  if (w < 5.0f) {
    w = w - 2.5f;
    p = 2.81022636e-08f;
    p = fmaf(p, w, 3.43273939e-07f);
    p = fmaf(p, w, -3.5233877e-06f);
    p = fmaf(p, w, -4.39150654e-06f);
    p = fmaf(p, w, 0.00021858087f);
    p = fmaf(p, w, -0.00125372503f);
    p = fmaf(p, w, -0.00417768164f);
    p = fmaf(p, w, 0.246640727f);
    p = fmaf(p, w, 1.50140941f);
  } else {
    w = sqrtf(w) - 3.0f;
    p = -0.000200214257f;
    p = fmaf(p, w, 0.000100950558f);
    p = fmaf(p, w, 0.00134934322f);
    p = fmaf(p, w, -0.00367342844f);
    p = fmaf(p, w, 0.00573950773f);
    p = fmaf(p, w, -0.0076224613f);
    p = fmaf(p, w, 0.00943887047f);
    p = fmaf(p, w, 1.00167406f);
    p = fmaf(p, w, 2.83297682f);
  }
  return p * x;
}

__global__ void prep_kernel(const float* __restrict__ log_var,
                            float* __restrict__ invvar,
                            float* __restrict__ stdv, int V) {
  int i = blockIdx.x * 256 + threadIdx.x;
  if (i < V) {
    float var = fmaxf(expf(log_var[i]), 1e-8f);
    invvar[i] = 1.0f / var;
    stdv[i] = sqrtf(var);
  }
}

// RTN-even f32 -> bf16 bits; also returns the bf16 value back as f32.
__device__ inline unsigned short rtn_bf16(float x, float& back) {
  uint32_t u = __float_as_uint(x);
  uint32_t r = u + 0x7fffu + ((u >> 16) & 1u);
  unsigned short s = (unsigned short)(r >> 16);
  back = __uint_as_float(((uint32_t)s) << 16);
  return s;
}

__device__ inline void split3(float x, unsigned short& s0, unsigned short& s1,
                              unsigned short& s2) {
  float b, r1, r2;
  s0 = rtn_bf16(x, b);  r1 = x - b;
  s1 = rtn_bf16(r1, b); r2 = r1 - b;
  s2 = rtn_bf16(r2, b);
}

// Split W (flat, natural [V][H] layout) into 3 bf16 planes for the V kernel.
__global__ __launch_bounds__(256)
void split_w_kernel(const float* __restrict__ W,
                    unsigned short* __restrict__ P0,
                    unsigned short* __restrict__ P1,
                    unsigned short* __restrict__ P2) {
  int gid = blockIdx.x * 256 + threadIdx.x;
  int base = gid * 4;
  float4 x = *reinterpret_cast<const float4*>(&W[base]);
  ushort4 a0, a1, a2;
  split3(x.x, a0.x, a1.x, a2.x);
  split3(x.y, a0.y, a1.y, a2.y);
  split3(x.z, a0.z, a1.z, a2.z);
  split3(x.w, a0.w, a1.w, a2.w);
  *reinterpret_cast<ushort4*>(&P0[base]) = a0;
  *reinterpret_cast<ushort4*>(&P1[base]) = a1;
  *reinterpret_cast<ushort4*>(&P2[base]) = a2;
}

// Split (invvar[k] * W[k][n]) into 3 bf16 planes stored TRANSPOSED [n][k].
// W is [3072][512] row-major. Thread: lane covers n = 64*bx + (tid&63),
// k = 16*by + (tid>>6)*4 .. +3.  Reads coalesced across lanes; writes 8B/plane.
__global__ __launch_bounds__(256)
void split_wl_kernel(const float* __restrict__ W, const float* __restrict__ invvar,
                     unsigned short* __restrict__ T0,
                     unsigned short* __restrict__ T1,
                     unsigned short* __restrict__ T2) {
  const int N = 512, K = 3072;
  const int n = blockIdx.x * 64 + (threadIdx.x & 63);
  const int kb = blockIdx.y * 16 + (threadIdx.x >> 6) * 4;
  ushort4 a0, a1, a2;
  {
    float w0 = W[(size_t)(kb + 0) * N + n] * invvar[kb + 0];
    float w1 = W[(size_t)(kb + 1) * N + n] * invvar[kb + 1];
    float w2 = W[(size_t)(kb + 2) * N + n] * invvar[kb + 2];
    float w3 = W[(size_t)(kb + 3) * N + n] * invvar[kb + 3];
    split3(w0, a0.x, a1.x, a2.x);
    split3(w1, a0.y, a1.y, a2.y);
    split3(w2, a0.z, a1.z, a2.z);
    split3(w3, a0.w, a1.w, a2.w);
  }
  size_t o = (size_t)n * K + kb;
  *reinterpret_cast<ushort4*>(&T0[o]) = a0;
  *reinterpret_cast<ushort4*>(&T1[o]) = a1;
  *reinterpret_cast<ushort4*>(&T2[o]) = a2;
}

// Initial A-planes: elementwise split of v_in (layout [4096][3072], kept).
__global__ __launch_bounds__(256)
void split_a_kernel(const float* __restrict__ Vin,
                    unsigned short* __restrict__ A0,
                    unsigned short* __restrict__ A1,
                    unsigned short* __restrict__ A2) {
  int gid = blockIdx.x * 256 + threadIdx.x;
  int base = gid * 4;
  float4 x = *reinterpret_cast<const float4*>(&Vin[base]);
  ushort4 a0, a1, a2;
  split3(x.x, a0.x, a1.x, a2.x);
  split3(x.y, a0.y, a1.y, a2.y);
  split3(x.z, a0.z, a1.z, a2.z);
  split3(x.w, a0.w, a1.w, a2.w);
  *reinterpret_cast<ushort4*>(&A0[base]) = a0;
  *reinterpret_cast<ushort4*>(&A1[base]) = a1;
  *reinterpret_cast<ushort4*>(&A2[base]) = a2;
}

// ---------------------------------------------------------------------------
// Kernel L-MFMA: logits = v @ (ivv*W) + b ; h = bernoulli(sigmoid(logits)).
// M=4096, N=512, K=3072. BM=BN=64, 4 waves (2x2 quadrants of 32x32), KT=32,
// 2-barrier dbuf. 6 magnitude-pruned passes: A0B0,A0B1,A1B0,A0B2,A1B1,A2B0.
// grid=512 XCD-swizzled (xcd=bid&7 owns 8 m-panels x all 8 n-blocks).
// ---------------------------------------------------------------------------
__global__ __launch_bounds__(256, 1)
void gemm_logit_mfma(const unsigned short* __restrict__ A0,
                     const unsigned short* __restrict__ A1,
                     const unsigned short* __restrict__ A2,
                     const unsigned short* __restrict__ T0,
                     const unsigned short* __restrict__ T1,
                     const unsigned short* __restrict__ T2,
                     const float* __restrict__ bias,
                     uint8_t* __restrict__ Hout, uint32_t kb0, uint32_t kb1) {
  const int N = 512, K = 3072;
  __shared__ __attribute__((aligned(16))) unsigned short As[2][3][64][40];
  __shared__ __attribute__((aligned(16))) unsigned short Bs[2][3][64][40];

  const int tid = threadIdx.x;
  const int bid = blockIdx.x;
  const int xcd = bid & 7;
  const int c = bid >> 3;
  const int mb = xcd * 8 + (c >> 3);     // 0..63
  const int nb = c & 7;                  // 0..7
  const int mBase = mb * 64, nBase = nb * 64;

  const int lane = tid & 63, w = tid >> 6;
  const int wr = w >> 1, wc = w & 1;
  const int lg = lane >> 4, lm = lane & 15;

  const int srow = tid >> 2;        // 0..63
  const int soff = (tid & 3) * 8;   // 0,8,16,24

  f32x4 acc00 = {0.f, 0.f, 0.f, 0.f};
  f32x4 acc01 = {0.f, 0.f, 0.f, 0.f};
  f32x4 acc10 = {0.f, 0.f, 0.f, 0.f};
  f32x4 acc11 = {0.f, 0.f, 0.f, 0.f};

  bf16x8 ra0, ra1, ra2, rb0, rb1, rb2;

#define LOADL(t) { \
  size_t ao = (size_t)(mBase + srow) * K + (t) * 32 + soff; \
  size_t bo = (size_t)(nBase + srow) * K + (t) * 32 + soff; \
  ra0 = *reinterpret_cast<const bf16x8*>(&A0[ao]); \
  ra1 = *reinterpret_cast<const bf16x8*>(&A1[ao]); \
  ra2 = *reinterpret_cast<const bf16x8*>(&A2[ao]); \
  rb0 = *reinterpret_cast<const bf16x8*>(&T0[bo]); \
  rb1 = *reinterpret_cast<const bf16x8*>(&T1[bo]); \
  rb2 = *reinterpret_cast<const bf16x8*>(&T2[bo]); }

#define STAGEL(p) { \
  *reinterpret_cast<bf16x8*>(&As[p][0][srow][soff]) = ra0; \
  *reinterpret_cast<bf16x8*>(&As[p][1][srow][soff]) = ra1; \
  *reinterpret_cast<bf16x8*>(&As[p][2][srow][soff]) = ra2; \
  *reinterpret_cast<bf16x8*>(&Bs[p][0][srow][soff]) = rb0; \
  *reinterpret_cast<bf16x8*>(&Bs[p][1][srow][soff]) = rb1; \
  *reinterpret_cast<bf16x8*>(&Bs[p][2][srow][soff]) = rb2; }

  LOADL(0)
  STAGEL(0)
  __syncthreads();

  int cur = 0;
  const int NT = K / 32;   // 96
  for (int t = 0; t < NT; ++t) {
    const bool more = (t + 1 < NT);
    if (more) LOADL(t + 1)

    bf16x8 a00 = *reinterpret_cast<const bf16x8*>(&As[cur][0][wr * 32 + lm][lg * 8]);
    bf16x8 a01 = *reinterpret_cast<const bf16x8*>(&As[cur][0][wr * 32 + 16 + lm][lg * 8]);
    bf16x8 a10 = *reinterpret_cast<const bf16x8*>(&As[cur][1][wr * 32 + lm][lg * 8]);
    bf16x8 a11 = *reinterpret_cast<const bf16x8*>(&As[cur][1][wr * 32 + 16 + lm][lg * 8]);
    bf16x8 a20 = *reinterpret_cast<const bf16x8*>(&As[cur][2][wr * 32 + lm][lg * 8]);
    bf16x8 a21 = *reinterpret_cast<const bf16x8*>(&As[cur][2][wr * 32 + 16 + lm][lg * 8]);
    bf16x8 b00 = *reinterpret_cast<const bf16x8*>(&Bs[cur][0][wc * 32 + lm][lg * 8]);
    bf16x8 b01 = *reinterpret_cast<const bf16x8*>(&Bs[cur][0][wc * 32 + 16 + lm][lg * 8]);
    bf16x8 b10 = *reinterpret_cast<const bf16x8*>(&Bs[cur][1][wc * 32 + lm][lg * 8]);
    bf16x8 b11 = *reinterpret_cast<const bf16x8*>(&Bs[cur][1][wc * 32 + 16 + lm][lg * 8]);
    bf16x8 b20 = *reinterpret_cast<const bf16x8*>(&Bs[cur][2][wc * 32 + lm][lg * 8]);
    bf16x8 b21 = *reinterpret_cast<const bf16x8*>(&Bs[cur][2][wc * 32 + 16 + lm][lg * 8]);

#define PASS(aa0, aa1, bb0, bb1) \
    acc00 = __builtin_amdgcn_mfma_f32_16x16x32_bf16(aa0, bb0, acc00, 0, 0, 0); \
    acc01 = __builtin_amdgcn_mfma_f32_16x16x32_bf16(aa0, bb1, acc01, 0, 0, 0); \
    acc10 = __builtin_amdgcn_mfma_f32_16x16x32_bf16(aa1, bb0, acc10, 0, 0, 0); \
    acc11 = __builtin_amdgcn_mfma_f32_16x16x32_bf16(aa1, bb1, acc11, 0, 0, 0);

    PASS(a00, a01, b00, b01)   // A0*B0
    PASS(a00, a01, b10, b11)   // A0*B1
    PASS(a10, a11, b00, b01)   // A1*B0
    PASS(a00, a01, b20, b21)   // A0*B2
    PASS(a10, a11, b10, b11)   // A1*B1
    PASS(a20, a21, b00, b01)   // A2*B0
#undef PASS

    if (more) {
      __syncthreads();
      STAGEL(cur ^ 1)
      __syncthreads();
      cur ^= 1;
    }
  }
#undef LOADL
#undef STAGEL

  const int col0 = nBase + wc * 32 + lm;
  const int col1 = col0 + 16;
  const float bias0 = bias[col0], bias1 = bias[col1];

#define HOUT(accv, r, rowv, colv, bv) { \
  int row = (rowv); int col = (colv); \
  float logit = accv[r] + (bv); \
  float p2 = 0.5f + 0.5f * tanhf(0.5f * logit); \
  uint32_t idx = (uint32_t)row * (uint32_t)N + (uint32_t)col; \
  float u = jax_uniform01(kb0, kb1, idx); \
  Hout[(size_t)row * N + col] = (u < p2) ? (uint8_t)1 : (uint8_t)0; }

#pragma unroll
  for (int r = 0; r < 4; ++r) {
    int row0 = mBase + wr * 32 + lg * 4 + r;
    int row1 = row0 + 16;
    HOUT(acc00, r, row0, col0, bias0)
    HOUT(acc01, r, row0, col1, bias1)
    HOUT(acc10, r, row1, col0, bias0)
    HOUT(acc11, r, row1, col1, bias1)
  }
#undef HOUT
}

// ---------------------------------------------------------------------------
// Kernel V-MFMA (R8-proven + optional A-plane emission): v = h@W^T + mu + nz*std.
// ---------------------------------------------------------------------------
__global__ __launch_bounds__(256, 1)
void gemm_v_mfma(const uint8_t* __restrict__ Hin,
                 const unsigned short* __restrict__ W0,
                 const unsigned short* __restrict__ W1,
                 const unsigned short* __restrict__ W2,
                 const float* __restrict__ muv, const float* __restrict__ stdv,
                 float* __restrict__ Vout,
                 unsigned short* __restrict__ A0,
                 unsigned short* __restrict__ A1,
                 unsigned short* __restrict__ A2,
                 uint32_t kn0, uint32_t kn1) {
  const int N = 3072, K = 512;
  __shared__ __attribute__((aligned(16))) unsigned short As[2][64][40];
  __shared__ __attribute__((aligned(16))) unsigned short Bs[2][3][64][40];

  const int tid = threadIdx.x;
  const int mBase = blockIdx.y * 64, nBase = blockIdx.x * 64;
  const int lane = tid & 63, w = tid >> 6;
  const int wr = w >> 1, wc = w & 1;
  const int lg = lane >> 4, lm = lane & 15;

  const int srow = tid >> 2;
  const int soff = (tid & 3) * 8;

  f32x4 acc00 = {0.f, 0.f, 0.f, 0.f};
  f32x4 acc01 = {0.f, 0.f, 0.f, 0.f};
  f32x4 acc10 = {0.f, 0.f, 0.f, 0.f};
  f32x4 acc11 = {0.f, 0.f, 0.f, 0.f};

  const __bf16 ONE = (__bf16)1.0f;
  const __bf16 ZERO = (__bf16)0.0f;

  uint64_t rh;
  bf16x8 rw0, rw1, rw2;

#define LOADV(t) { \
  int k0 = (t) * 32; \
  rh  = *reinterpret_cast<const uint64_t*>(&Hin[(size_t)(mBase + srow) * K + k0 + soff]); \
  rw0 = *reinterpret_cast<const bf16x8*>(&W0[(size_t)(nBase + srow) * K + k0 + soff]); \
  rw1 = *reinterpret_cast<const bf16x8*>(&W1[(size_t)(nBase + srow) * K + k0 + soff]); \
  rw2 = *reinterpret_cast<const bf16x8*>(&W2[(size_t)(nBase + srow) * K + k0 + soff]); }

#define STAGEV(p) { \
  bf16x8 hv; \
  hv[0] = ((rh >> 0)  & 0xffu) ? ONE : ZERO; \
  hv[1] = ((rh >> 8)  & 0xffu) ? ONE : ZERO; \
  hv[2] = ((rh >> 16) & 0xffu) ? ONE : ZERO; \
  hv[3] = ((rh >> 24) & 0xffu) ? ONE : ZERO; \
  hv[4] = ((rh >> 32) & 0xffu) ? ONE : ZERO; \
  hv[5] = ((rh >> 40) & 0xffu) ? ONE : ZERO; \
  hv[6] = ((rh >> 48) & 0xffu) ? ONE : ZERO; \
  hv[7] = ((rh >> 56) & 0xffu) ? ONE : ZERO; \
  *reinterpret_cast<bf16x8*>(&As[p][srow][soff])    = hv; \
  *reinterpret_cast<bf16x8*>(&Bs[p][0][srow][soff]) = rw0; \
  *reinterpret_cast<bf16x8*>(&Bs[p][1][srow][soff]) = rw1; \
  *reinterpret_cast<bf16x8*>(&Bs[p][2][srow][soff]) = rw2; }

  LOADV(0)
  STAGEV(0)
  __syncthreads();

  int cur = 0;
  const int NT = K / 32;   // 16
  for (int t = 0; t < NT; ++t) {
    const bool more = (t + 1 < NT);
    if (more) LOADV(t + 1)

    bf16x8 a0 = *reinterpret_cast<const bf16x8*>(&As[cur][wr * 32 + lm][lg * 8]);
    bf16x8 a1 = *reinterpret_cast<const bf16x8*>(&As[cur][wr * 32 + 16 + lm][lg * 8]);
    bf16x8 b00 = *reinterpret_cast<const bf16x8*>(&Bs[cur][0][wc * 32 + lm][lg * 8]);
    bf16x8 b01 = *reinterpret_cast<const bf16x8*>(&Bs[cur][0][wc * 32 + 16 + lm][lg * 8]);
    bf16x8 b10 = *reinterpret_cast<const bf16x8*>(&Bs[cur][1][wc * 32 + lm][lg * 8]);
    bf16x8 b11 = *reinterpret_cast<const bf16x8*>(&Bs[cur][1][wc * 32 + 16 + lm][lg * 8]);
    bf16x8 b20 = *reinterpret_cast<const bf16x8*>(&Bs[cur][2][wc * 32 + lm][lg * 8]);
    bf16x8 b21 = *reinterpret_cast<const bf16x8*>(&Bs[cur][2][wc * 32 + 16 + lm][lg * 8]);

    acc00 = __builtin_amdgcn_mfma_f32_16x16x32_bf16(a0, b00, acc00, 0, 0, 0);
    acc01 = __builtin_amdgcn_mfma_f32_16x16x32_bf16(a0, b01, acc01, 0, 0, 0);
    acc10 = __builtin_amdgcn_mfma_f32_16x16x32_bf16(a1, b00, acc10, 0, 0, 0);
    acc11 = __builtin_amdgcn_mfma_f32_16x16x32_bf16(a1, b01, acc11, 0, 0, 0);
    acc00 = __builtin_amdgcn_mfma_f32_16x16x32_bf16(a0, b10, acc00, 0, 0, 0);
    acc01 = __builtin_amdgcn_mfma_f32_16x16x32_bf16(a0, b11, acc01, 0, 0, 0);
    acc10 = __builtin_amdgcn_mfma_f32_16x16x32_bf16(a1, b10, acc10, 0, 0, 0);
    acc11 = __builtin_amdgcn_mfma_f32_16x16x32_bf16(a1, b11, acc11, 0, 0, 0);
    acc00 = __builtin_amdgcn_mfma_f32_16x16x32_bf16(a0, b20, acc00, 0, 0, 0);
    acc01 = __builtin_amdgcn_mfma_f32_16x16x32_bf16(a0, b21, acc01, 0, 0, 0);
    acc10 = __builtin_amdgcn_mfma_f32_16x16x32_bf16(a1, b20, acc10, 0, 0, 0);
    acc11 = __builtin_amdgcn_mfma_f32_16x16x32_bf16(a1, b21, acc11, 0, 0, 0);

    if (more) {
      __syncthreads();
      STAGEV(cur ^ 1)
      __syncthreads();
      cur ^= 1;
    }
  }
#undef LOADV
#undef STAGEV

  const float LO = -0.99999994f;
  const float SQRT2 = 1.41421356237f;
  const int col0 = nBase + wc * 32 + lm;
  const int col1 = col0 + 16;
  const float mu0 = muv[col0], mu1 = muv[col1];
  const float sd0 = stdv[col0], sd1 = stdv[col1];
  const bool emitA = (A0 != nullptr);

#define VOUTM(accv, r, rowv, colv, muvv, sdvv) { \
  int row = (rowv); int col = (colv); \
  float m_v = accv[r] + (muvv); \
  uint32_t idx = (uint32_t)row * (uint32_t)N + (uint32_t)col; \
  float f = jax_uniform01(kn0, kn1, idx); \
  float u = fmaxf(LO, fmaf(f, 2.0f, LO)); \
  float nz = SQRT2 * erfinv_xla(u); \
  float vv = m_v + nz * (sdvv); \
  Vout[(size_t)row * N + col] = vv; \
  if (emitA) { \
    unsigned short s0, s1, s2; \
    split3(vv, s0, s1, s2); \
    size_t ao = (size_t)row * N + col; \
    A0[ao] = s0; A1[ao] = s1; A2[ao] = s2; \
  } }

#pragma unroll
  for (int r = 0; r < 4; ++r) {
    int row0 = mBase + wr * 32 + lg * 4 + r;
    int row1 = row0 + 16;
    VOUTM(acc00, r, row0, col0, mu0, sd0)
    VOUTM(acc01, r, row0, col1, mu1, sd1)
    VOUTM(acc10, r, row1, col0, mu0, sd0)
    VOUTM(acc11, r, row1, col1, mu1, sd1)
  }
#undef VOUTM
}

// ---------------------------------------------------------------------------
// Fallback fp32 kernels (R7-proven) — used when ws_size is too small.
// ---------------------------------------------------------------------------
__global__ __launch_bounds__(256, 1)
void gemm_logit_bern(const float* __restrict__ Vin, const float* __restrict__ Wm,
                     const float* __restrict__ bias, const float* __restrict__ invvar,
                     uint8_t* __restrict__ Hout, uint32_t kb0, uint32_t kb1) {
  const int N = 512, K = 3072;
  const int KT = 32;
  __shared__ float As[2][KT][68];
  __shared__ float Bs[2][KT][64];

  const int tid = threadIdx.x;
  const int bid = blockIdx.x;
  const int xcd = bid & 7;
  const int c = bid >> 3;
  const int mb = xcd * 8 + (c >> 3);
  const int nb = c & 7;
  const int mBase = mb * 64, nBase = nb * 64;

  const int tx = tid & 15, ty = tid >> 4;
  const int am = tid >> 2;
  const int ak = (tid & 3) * 4;
  const int bk = tid >> 4;
  const int bn = (tid & 15) * 4;

  float acc[4][4] = {};
  float4 ra0, ra1, riv0, riv1, rb0, rb1;

#define LOADL(t) { \
  int k0 = (t) * KT; \
  ra0  = *reinterpret_cast<const float4*>(&Vin[(size_t)(mBase + am) * K + k0 + ak]); \
  ra1  = *reinterpret_cast<const float4*>(&Vin[(size_t)(mBase + am) * K + k0 + 16 + ak]); \
  riv0 = *reinterpret_cast<const float4*>(&invvar[k0 + ak]); \
  riv1 = *reinterpret_cast<const float4*>(&invvar[k0 + 16 + ak]); \
  rb0  = *reinterpret_cast<const float4*>(&Wm[(size_t)(k0 + bk) * N + nBase + bn]); \
  rb1  = *reinterpret_cast<const float4*>(&Wm[(size_t)(k0 + 16 + bk) * N + nBase + bn]); }

#define STOREL(p) { \
  As[p][ak + 0][am]      = ra0.x * riv0.x; \
  As[p][ak + 1][am]      = ra0.y * riv0.y; \
  As[p][ak + 2][am]      = ra0.z * riv0.z; \
  As[p][ak + 3][am]      = ra0.w * riv0.w; \
  As[p][ak + 16][am]     = ra1.x * riv1.x; \
  As[p][ak + 17][am]     = ra1.y * riv1.y; \
  As[p][ak + 18][am]     = ra1.z * riv1.z; \
  As[p][ak + 19][am]     = ra1.w * riv1.w; \
  *reinterpret_cast<float4*>(&Bs[p][bk][bn])      = rb0; \
  *reinterpret_cast<float4*>(&Bs[p][bk + 16][bn]) = rb1; }

  LOADL(0)
  int p = 0;
  const int NT = K / KT;
  for (int t = 0; t < NT; ++t) {
    STOREL(p)
    if (t + 1 < NT) LOADL(t + 1)
    __syncthreads();
#pragma unroll
    for (int kk = 0; kk < KT; ++kk) {
      float4 x = *reinterpret_cast<const float4*>(&As[p][kk][ty * 4]);
      float4 y = *reinterpret_cast<const float4*>(&Bs[p][kk][tx * 4]);
#define LROW(i, a) \
      acc[i][0] = fmaf(a, y.x, acc[i][0]); \
      acc[i][1] = fmaf(a, y.y, acc[i][1]); \
      acc[i][2] = fmaf(a, y.z, acc[i][2]); \
      acc[i][3] = fmaf(a, y.w, acc[i][3]);
      LROW(0, x.x) LROW(1, x.y) LROW(2, x.z) LROW(3, x.w)
#undef LROW
    }
    p ^= 1;
  }
#undef LOADL
#undef STOREL

#pragma unroll
  for (int i = 0; i < 4; ++i) {
    int row = mBase + ty * 4 + i;
    uint32_t hp = 0;
#pragma unroll
    for (int j = 0; j < 4; ++j) {
      int col = nBase + tx * 4 + j;
      float logit = acc[i][j] + bias[col];
      float p2 = 0.5f + 0.5f * tanhf(0.5f * logit);
      uint32_t idx = (uint32_t)row * (uint32_t)N + (uint32_t)col;
      float u = jax_uniform01(kb0, kb1, idx);
      hp |= ((u < p2) ? 1u : 0u) << (8 * j);
    }
    *reinterpret_cast<uint32_t*>(&Hout[(size_t)row * N + nBase + tx * 4]) = hp;
  }
}

__global__ __launch_bounds__(256, 2)
void gemm_v_sample(const uint8_t* __restrict__ Hin, const float* __restrict__ Wm,
                   const float* __restrict__ muv, const float* __restrict__ stdv,
                   float* __restrict__ Vout, uint32_t kn0, uint32_t kn1) {
  const int N = 3072, K = 512;
  const int KT = 16;
  __shared__ float As[2][KT][132];
  __shared__ float Bs[2][KT][68];

  const int tid = threadIdx.x;
  const int mBase = blockIdx.y * 128, nBase = blockIdx.x * 64;
  const int tx = tid & 15, ty = tid >> 4;
  const int am = tid >> 1;
  const int ah = (tid & 1) * 8;
  const int bn = tid >> 2;
  const int bq = (tid & 3) * 4;

  float acc[8][4] = {};
  uint32_t rh0, rh1;
  float4 rb;
  {
    const uint32_t* hp_ = reinterpret_cast<const uint32_t*>(&Hin[(size_t)(mBase + am) * K + ah]);
    rh0 = hp_[0]; rh1 = hp_[1];
  }
  rb = *reinterpret_cast<const float4*>(&Wm[(size_t)(nBase + bn) * K + bq]);

#define STAGE_V(buf) { \
  As[buf][ah + 0][am] = (float)((rh0 >> 0) & 0xffu); \
  As[buf][ah + 1][am] = (float)((rh0 >> 8) & 0xffu); \
  As[buf][ah + 2][am] = (float)((rh0 >> 16) & 0xffu); \
  As[buf][ah + 3][am] = (float)((rh0 >> 24) & 0xffu); \
  As[buf][ah + 4][am] = (float)((rh1 >> 0) & 0xffu); \
  As[buf][ah + 5][am] = (float)((rh1 >> 8) & 0xffu); \
  As[buf][ah + 6][am] = (float)((rh1 >> 16) & 0xffu); \
  As[buf][ah + 7][am] = (float)((rh1 >> 24) & 0xffu); \
  Bs[buf][bq + 0][bn] = rb.x; \
  Bs[buf][bq + 1][bn] = rb.y; \
  Bs[buf][bq + 2][bn] = rb.z; \
  Bs[buf][bq + 3][bn] = rb.w; }

  STAGE_V(0)
  __syncthreads();

  int cur = 0;
  const int NT = K / KT;
  for (int t = 0; t < NT; ++t) {
    const bool more = (t + 1 < NT);
    if (more) {
      int k0 = (t + 1) * KT;
      const uint32_t* hp_ = reinterpret_cast<const uint32_t*>(&Hin[(size_t)(mBase + am) * K + k0 + ah]);
      rh0 = hp_[0]; rh1 = hp_[1];
      rb = *reinterpret_cast<const float4*>(&Wm[(size_t)(nBase + bn) * K + k0 + bq]);
    }
#pragma unroll
    for (int kk = 0; kk < KT; ++kk) {
      float4 x0 = *reinterpret_cast<const float4*>(&As[cur][kk][ty * 8]);
      float4 x1 = *reinterpret_cast<const float4*>(&As[cur][kk][ty * 8 + 4]);
      float4 y  = *reinterpret_cast<const float4*>(&Bs[cur][kk][tx * 4]);
#define VROW(i, a) \
      acc[i][0] = fmaf(a, y.x, acc[i][0]); \
      acc[i][1] = fmaf(a, y.y, acc[i][1]); \
      acc[i][2] = fmaf(a, y.z, acc[i][2]); \
      acc[i][3] = fmaf(a, y.w, acc[i][3]);
      VROW(0, x0.x) VROW(1, x0.y) VROW(2, x0.z) VROW(3, x0.w)
      VROW(4, x1.x) VROW(5, x1.y) VROW(6, x1.z) VROW(7, x1.w)
#undef VROW
    }
    if (more) {
      __syncthreads();
      STAGE_V(cur ^ 1)
      __syncthreads();
      cur ^= 1;
    }
  }
#undef STAGE_V

  const float LO = -0.99999994f;
  const float SQRT2 = 1.41421356237f;
  const float4 mu4 = *reinterpret_cast<const float4*>(&muv[nBase + tx * 4]);
  const float4 sd4 = *reinterpret_cast<const float4*>(&stdv[nBase + tx * 4]);
  const float mur[4] = {mu4.x, mu4.y, mu4.z, mu4.w};
  const float sdr[4] = {sd4.x, sd4.y, sd4.z, sd4.w};
#pragma unroll
  for (int i = 0; i < 8; ++i) {
    int row = mBase + ty * 8 + i;
    float o0, o1, o2, o3;
#define VOUT(j, dst) { \
      int col = nBase + tx * 4 + j; \
      float m_v = acc[i][j] + mur[j]; \
      uint32_t idx = (uint32_t)row * (uint32_t)N + (uint32_t)col; \
      float f = jax_uniform01(kn0, kn1, idx); \
      float u = fmaxf(LO, fmaf(f, 2.0f, LO)); \
      float nz = SQRT2 * erfinv_xla(u); \
      dst = m_v + nz * sdr[j]; }
    VOUT(0, o0) VOUT(1, o1) VOUT(2, o2) VOUT(3, o3)
#undef VOUT
    float4 s = {o0, o1, o2, o3};
    *reinterpret_cast<float4*>(&Vout[(size_t)row * N + nBase + tx * 4]) = s;
  }
}

extern "C" void kernel_launch(void* const* d_in, const int* in_sizes, int n_in,
                              void* d_out, int out_size, void* d_ws, size_t ws_size,
                              hipStream_t stream) {
  const int B = 4096, V = 3072, H = 512, NUM_STEPS = 8;
  const float* v_in    = (const float*)d_in[0];
  const float* W       = (const float*)d_in[1];
  const float* b       = (const float*)d_in[2];
  const float* mu      = (const float*)d_in[3];
  const float* log_var = (const float*)d_in[4];
  float* out = (float*)d_out;

  const size_t WELEMS = (size_t)V * H;           // 1,572,864
  const size_t AELEMS = (size_t)B * V;           // 12,582,912
  // Full layout: invvar|stdv | WV0..2 | WLT0..2 | A0..2 | h
  const size_t NEED_FULL = 24576 + 6 * WELEMS * 2 + 3 * AELEMS * 2 + (size_t)B * H;
  const size_t NEED_MID  = 24576 + 3 * WELEMS * 2 + (size_t)B * H;
  const int mode = (ws_size >= NEED_FULL) ? 2 : (ws_size >= NEED_MID) ? 1 : 0;

  float* invvar = (float*)d_ws;
  float* stdv   = invvar + V;
  unsigned short* WV0 = (unsigned short*)(stdv + V);
  unsigned short* WV1 = WV0 + WELEMS;
  unsigned short* WV2 = WV1 + WELEMS;
  unsigned short* WT0 = WV2 + WELEMS;
  unsigned short* WT1 = WT0 + WELEMS;
  unsigned short* WT2 = WT1 + WELEMS;
  unsigned short* A0  = WT2 + WELEMS;
  unsigned short* A1  = A0 + AELEMS;
  unsigned short* A2  = A1 + AELEMS;
  uint8_t* h;
  if (mode == 2)      h = (uint8_t*)(A2 + AELEMS);
  else if (mode == 1) h = (uint8_t*)(WV2 + WELEMS);
  else                h = (uint8_t*)(stdv + V);

  uint32_t k0a, k0b, kl0, kl1;
  threefry2x32(0u, 42u, 0u, 0u, k0a, k0b);
  threefry2x32(0u, 42u, 0u, 1u, kl0, kl1);
  uint32_t kn0[NUM_STEPS], kn1[NUM_STEPS], kb0[NUM_STEPS], kb1[NUM_STEPS];
  for (int t = 0; t < NUM_STEPS; ++t) {
    uint32_t kt0, kt1;
    threefry2x32(kl0, kl1, 0u, (uint32_t)t, kt0, kt1);
    threefry2x32(kt0, kt1, 0u, 0u, kn0[t], kn1[t]);
    threefry2x32(kt0, kt1, 0u, 1u, kb0[t], kb1[t]);
  }

  prep_kernel<<<(V + 255) / 256, 256, 0, stream>>>(log_var, invvar, stdv, V);

  dim3 gridL32(512);               // fp32 L
  dim3 gridLm(512);                // MFMA L (XCD-swizzled internally)
  dim3 gridVm(V / 64, B / 64);     // (48, 64)
  dim3 gridVf(V / 64, B / 128);    // (48, 32)

  if (mode == 2) {
    split_w_kernel<<<(int)(WELEMS / 4 / 256), 256, 0, stream>>>(W, WV0, WV1, WV2);
    split_wl_kernel<<<dim3(H / 64, V / 16), 256, 0, stream>>>(W, invvar, WT0, WT1, WT2);
    split_a_kernel<<<(int)(AELEMS / 4 / 256), 256, 0, stream>>>(v_in, A0, A1, A2);

    gemm_logit_mfma<<<gridLm, 256, 0, stream>>>(A0, A1, A2, WT0, WT1, WT2, b, h, k0a, k0b);
    for (int t = 0; t < NUM_STEPS; ++t) {
      float* vt = out + (size_t)t * B * V;
      gemm_v_mfma<<<gridVm, 256, 0, stream>>>(h, WV0, WV1, WV2, mu, stdv, vt,
                                              A0, A1, A2, kn0[t], kn1[t]);
      if (t < NUM_STEPS - 1) {
        gemm_logit_mfma<<<gridLm, 256, 0, stream>>>(A0, A1, A2, WT0, WT1, WT2, b, h, kb0[t], kb1[t]);
      }
    }
  } else if (mode == 1) {
    split_w_kernel<<<(int)(WELEMS / 4 / 256), 256, 0, stream>>>(W, WV0, WV1, WV2);
    gemm_logit_bern<<<gridL32, 256, 0, stream>>>(v_in, W, b, invvar, h, k0a, k0b);
    for (int t = 0; t < NUM_STEPS; ++t) {
      float* vt = out + (size_t)t * B * V;
      gemm_v_mfma<<<gridVm, 256, 0, stream>>>(h, WV0, WV1, WV2, mu, stdv, vt,
                                              nullptr, nullptr, nullptr, kn0[t], kn1[t]);
      if (t < NUM_STEPS - 1) {
        gemm_logit_bern<<<gridL32, 256, 0, stream>>>(vt, W, b, invvar, h, kb0[t], kb1[t]);
      }
    }
  } else {
    gemm_logit_bern<<<gridL32, 256, 0, stream>>>(v_in, W, b, invvar, h, k0a, k0b);
    for (int t = 0; t < NUM_STEPS; ++t) {
      float* vt = out + (size_t)t * B * V;
      gemm_v_sample<<<gridVf, 256, 0, stream>>>(h, W, mu, stdv, vt, kn0[t], kn1[t]);
      if (t < NUM_STEPS - 1) {
        gemm_logit_bern<<<gridL32, 256, 0, stream>>>(vt, W, b, invvar, h, kb0[t], kb1[t]);
      }
    }
  }
}